// Round 7
// baseline (318.434 us; speedup 1.0000x reference)
//
#include <hip/hip_runtime.h>
#include <hip/hip_bf16.h>
#include <stdint.h>

#define BB 4
#define SS 2048
#define HH 1024
#define NHH 16
#define HDD 64
#define M_TOT (BB*SS)          // 8192

// workspace layout (ushort/bf16 element offsets)
#define XB_OFF 0                              // hidden bf16 [8192][1024]
#define WT_OFF (M_TOT*HH)                     // Wq^T,Wk^T,Wv^T bf16 [3][N=1024][K=1024]
#define Q_OFF  (WT_OFF + 3*HH*HH)             // Q  [B][NH][S][HD]  (pre-scaled by 0.125*log2e!)
#define K_OFF  (Q_OFF + BB*NHH*SS*HDD)        // K  [B][NH][S][HD]
#define VT_OFF (K_OFF + BB*NHH*SS*HDD)        // Vt [B][NH][HD][S]  (transposed)

typedef short bf16x8 __attribute__((ext_vector_type(8)));
typedef float f32x4  __attribute__((ext_vector_type(4)));

__device__ inline unsigned short f2bf(float f){
  unsigned u = __float_as_uint(f);
  u += 0x7fffu + ((u >> 16) & 1u);   // RNE
  return (unsigned short)(u >> 16);
}
__device__ inline unsigned pk2bf(float lo, float hi){
  float2 t; t.x = lo; t.y = hi;
  __hip_bfloat162 h = __float22bfloat162_rn(t);
  return *(unsigned*)&h;
}

// async global->LDS, 16B per lane
__device__ __forceinline__ void ld_g2l_16(const unsigned short* g, unsigned short* l){
  __builtin_amdgcn_global_load_lds(
      (const __attribute__((address_space(1))) void*)g,
      (__attribute__((address_space(3))) void*)l, 16, 0, 0);
}

// ---------------- kernel 1: fused X->bf16 + W->WT bf16 (one launch) ----------------
// blocks [0, 8192): convert X (float4/thread). blocks [8192, 8960): transpose W tiles.
__global__ void convert_all(const float* __restrict__ hs, unsigned short* __restrict__ xb,
                            const float* __restrict__ wq, const float* __restrict__ wk,
                            const float* __restrict__ wv, unsigned short* __restrict__ wt){
  __shared__ unsigned short t[64][65];
  const int tid = threadIdx.x;
  if (blockIdx.x < 8192){
    const int i = blockIdx.x*256 + tid;
    float4 v = ((const float4*)hs)[i];
    ushort4 o;
    o.x = f2bf(v.x); o.y = f2bf(v.y); o.z = f2bf(v.z); o.w = f2bf(v.w);
    ((ushort4*)xb)[i] = o;
    return;
  }
  const int wtb = blockIdx.x - 8192;
  const int z   = wtb >> 8;              // 256 tiles per z
  const int rem = wtb & 255;
  const int kb  = (rem & 15)*64, nb = (rem >> 4)*64;
  const float* W = (z==0) ? wq : ((z==1) ? wk : wv);
  unsigned short* WT = wt + z*HH*HH;
  #pragma unroll
  for (int i = 0; i < 16; i++){
    const int idx = i*256 + tid;
    const int r = idx >> 6, c = idx & 63;
    t[r][c] = f2bf(W[(kb + r)*HH + nb + c]);
  }
  __syncthreads();
  #pragma unroll
  for (int i = 0; i < 16; i++){
    const int idx = i*256 + tid;
    const int n = idx >> 6, k = idx & 63;
    WT[(nb + n)*HH + kb + k] = t[k][n];
  }
}

// ---------------- kernel 2: QKV projection GEMM ----------------
// R6: R5's verified 3-buffer / depth-2 / counted-vmcnt(4) schedule UNCHANGED, plus
// __launch_bounds__(256, 4) to force VGPR<=128 (was 172 -> 2 waves/SIMD cap, 11%
// occupancy, latency-exposed). LDS 48KB caps at 3 blocks/CU = 12 waves/CU (37.5%).
// (a) per iter: vmcnt(4) [own stage(k) done] -> s_barrier [all waves' stage(k)
//     visible] -> stage(k+2) -> ds_read(buf k%3) -> MFMA. vmcnt BEFORE barrier is
//     load-visibility-critical (each wave drains its own stage before the barrier
//     publishes the buffer).
// (b) LDS XOR swizzle (16B col: p' = p ^ ((row>>1)&3)) via pre-swizzled global
//     source (rule 21) -> bank conflicts measured 0 (R5).
// z in {0,1}: MFMA operands swapped -> lane holds 4 consecutive d -> ushort4 stores.
// z==2 (V^T): lane holds 4 consecutive s -> ushort4 stores.
__global__ __launch_bounds__(256, 4) void qkv_gemm(
    const unsigned short* __restrict__ ws16, unsigned short* __restrict__ wsq,
    const float* __restrict__ bq, const float* __restrict__ bk, const float* __restrict__ bv,
    const float* __restrict__ qe, const float* __restrict__ ke, const float* __restrict__ ve,
    const int* __restrict__ idxp){
  __shared__ unsigned short al[3*128*32];   // 3 x 8KB
  __shared__ unsigned short bl[3*128*32];   // 3 x 8KB

  const unsigned short* Xb = ws16 + XB_OFF;
  const int z = blockIdx.z;
  const unsigned short* Wt = ws16 + WT_OFF + z*HH*HH;
  const float* bias = (z==0) ? bq : ((z==1) ? bk : bv);
  const float* emb  = (z==0) ? qe : ((z==1) ? ke : ve);

  const int tid  = threadIdx.x;
  const int wv   = tid >> 6;
  const int ln   = tid & 63;
  const int quad = ln >> 4;
  const int l15  = ln & 15;
  const int m0 = blockIdx.x * 128;
  const int n0 = blockIdx.y * 128;
  const int wm = wv & 1, wn = wv >> 1;
  const int swz = (l15 >> 1) & 3;            // read-side 16B-col XOR

  // staging: wave wv stages rows [wv*32, wv*32+32) of each 128x32 tile.
  // source piece pre-swizzled: physical piece (ln&3) at row sr holds logical
  // piece (ln&3) ^ ((sr>>1)&3); (sr>>1)&3 == (ln>>3)&3 for both sr0 and sr1.
  const int sr0 = wv*32 + (ln >> 2);
  const int sr1 = sr0 + 16;
  const int sk  = (((ln & 3) ^ ((ln >> 3) & 3))) * 8;
  const unsigned short* ga0 = &Xb[(size_t)(m0 + sr0)*HH + sk];
  const unsigned short* ga1 = &Xb[(size_t)(m0 + sr1)*HH + sk];
  const unsigned short* gb0 = &Wt[(size_t)(n0 + sr0)*HH + sk];
  const unsigned short* gb1 = &Wt[(size_t)(n0 + sr1)*HH + sk];
  unsigned short* alw = &al[wv*1024];        // wave's linear dest (+lane*16B)
  unsigned short* blw = &bl[wv*1024];

  f32x4 acc[4][4] = {};

  // prologue: stage k=0 -> buf0, k=1 -> buf1 (8 loads in flight)
  ld_g2l_16(ga0,      alw);        ld_g2l_16(ga1,      alw + 512);
  ld_g2l_16(gb0,      blw);        ld_g2l_16(gb1,      blw + 512);
  ld_g2l_16(ga0 + 32, alw + 4096); ld_g2l_16(ga1 + 32, alw + 4096 + 512);
  ld_g2l_16(gb0 + 32, blw + 4096); ld_g2l_16(gb1 + 32, blw + 4096 + 512);

#define K_ITER(K, CUR, SB, DO_STAGE, VM)                                      \
  {                                                                           \
    asm volatile("s_waitcnt vmcnt(" #VM ")" ::: "memory");                    \
    __builtin_amdgcn_s_barrier();                                             \
    if (DO_STAGE){                                                            \
      const int koff = ((K) + 2) * 32;                                        \
      ld_g2l_16(ga0 + koff, alw + (SB)*4096);                                 \
      ld_g2l_16(ga1 + koff, alw + (SB)*4096 + 512);                           \
      ld_g2l_16(gb0 + koff, blw + (SB)*4096);                                 \
      ld_g2l_16(gb1 + koff, blw + (SB)*4096 + 512);                           \
    }                                                                         \
    const unsigned short* alc = &al[(CUR)*4096];                              \
    const unsigned short* blc = &bl[(CUR)*4096];                              \
    bf16x8 af[4], bf[4];                                                      \
    _Pragma("unroll")                                                         \
    for (int i = 0; i < 4; i++){                                              \
      af[i] = *(const bf16x8*)&alc[(wm*64 + i*16 + l15)*32 + (quad ^ swz)*8]; \
      bf[i] = *(const bf16x8*)&blc[(wn*64 + i*16 + l15)*32 + (quad ^ swz)*8]; \
    }                                                                         \
    if (z == 2){                                                              \
      _Pragma("unroll")                                                       \
      for (int mi = 0; mi < 4; mi++)                                          \
        _Pragma("unroll")                                                     \
        for (int ni = 0; ni < 4; ni++)                                        \
          acc[mi][ni] = __builtin_amdgcn_mfma_f32_16x16x32_bf16(af[mi], bf[ni], acc[mi][ni], 0, 0, 0); \
    } else {                                                                  \
      _Pragma("unroll")                                                       \
      for (int mi = 0; mi < 4; mi++)                                          \
        _Pragma("unroll")                                                     \
        for (int ni = 0; ni < 4; ni++)                                        \
          acc[mi][ni] = __builtin_amdgcn_mfma_f32_16x16x32_bf16(bf[ni], af[mi], acc[mi][ni], 0, 0, 0); \
    }                                                                         \
  }

  for (int k = 0; k < 30; k += 3){
    K_ITER(k,     0, 2, 1, 4)
    K_ITER(k + 1, 1, 0, 1, 4)
    K_ITER(k + 2, 2, 1, 1, 4)
  }
  K_ITER(30, 0, 0, 0, 4)   // no stage; wait stage(30)
  K_ITER(31, 1, 0, 0, 0)   // no stage; drain stage(31)
#undef K_ITER

  const int index = idxp[0];
  if (z == 2){
    // V^T: [bh][d][s], lane holds 4 consecutive s_ -> ushort4
    #pragma unroll
    for (int ni = 0; ni < 4; ni++){
      const int n = n0 + wn*64 + ni*16 + l15;
      const float biasv = bias[n] + emb[index*HH + n];
      const int h = n >> 6, d = n & 63;
      #pragma unroll
      for (int mi = 0; mi < 4; mi++){
        const int g  = m0 + wm*64 + mi*16 + quad*4;   // 4 consecutive s (4-aligned)
        const int b_ = g >> 11;
        const int s_ = g & (SS - 1);
        const int bh = b_*NHH + h;
        const f32x4 a = acc[mi][ni];
        ushort4 o;
        o.x = f2bf(a[0] + biasv); o.y = f2bf(a[1] + biasv);
        o.z = f2bf(a[2] + biasv); o.w = f2bf(a[3] + biasv);
        *(ushort4*)&wsq[VT_OFF + (size_t)(bh*HDD + d)*SS + s_] = o;
      }
    }
  } else {
    // Q/K: [bh][s][d], swapped acc: lane holds 4 consecutive d at fixed s -> ushort4
    const float oscale = (z==0) ? 0.18033688011112042f : 1.0f;  // 0.125*log2(e)
    const size_t obase = (z==0) ? (size_t)Q_OFF : (size_t)K_OFF;
    #pragma unroll
    for (int mi = 0; mi < 4; mi++){
      const int sg = m0 + wm*64 + mi*16 + l15;        // s-row (from B-operand col)
      const int b_ = sg >> 11;
      const int s_ = sg & (SS - 1);
      #pragma unroll
      for (int ni = 0; ni < 4; ni++){
        const int nb = n0 + wn*64 + ni*16 + quad*4;   // 4 consecutive n (4-aligned)
        const int h  = nb >> 6, d0 = nb & 63;         // no h-cross (d0 % 4 == 0)
        const int bh = b_*NHH + h;
        const float4 b4 = *(const float4*)&bias[nb];
        const float4 e4 = *(const float4*)&emb[index*HH + nb];
        const f32x4 a = acc[mi][ni];
        ushort4 o;
        o.x = f2bf((a[0] + b4.x + e4.x) * oscale);
        o.y = f2bf((a[1] + b4.y + e4.y) * oscale);
        o.z = f2bf((a[2] + b4.z + e4.z) * oscale);
        o.w = f2bf((a[3] + b4.w + e4.w) * oscale);
        *(ushort4*)&wsq[obase + (size_t)(bh*SS + s_)*HDD + d0] = o;
      }
    }
  }
}

// ---------------- kernel 3: flash attention, 16q/wave, 8-wave blocks ----------------
// (R2 known-good version: 112 µs measured.)
#define ST_P 40   // P^T row stride (shorts): 80B
__global__ __launch_bounds__(512, 6) void attn_mfma(
    const unsigned short* __restrict__ ws16,
    const float* __restrict__ mask, float* __restrict__ out){
  __shared__ __align__(16) unsigned short kb[2][32*64];   // [kt][d], swizzled, 2x4KB
  __shared__ __align__(16) unsigned short vb[2][64*32];   // [d][kt], linear,   2x4KB
  __shared__ __align__(16) unsigned short pb[8][16*ST_P]; // per-wave P^T [q][kt], 10.24KB
  __shared__ __align__(16) float mlds[SS];                // mask row * log2e, 8KB

  const int tid  = threadIdx.x;
  const int wave = tid >> 6;
  const int lane = tid & 63;
  const int quad = lane >> 4;
  const int l15  = lane & 15;

  // XCD-aware swizzle (bijective: 1024 % 8 == 0): each head's 16 blocks on one XCD.
  const int bid  = (blockIdx.x & 7)*128 + (blockIdx.x >> 3);
  const int qb   = bid & 15;                 // 16 q-blocks of 128 rows per bh
  const int bh   = bid >> 4;
  const int b    = bh >> 4, h = bh & 15;
  const int q0   = qb*128 + wave*16;         // this wave's first q row
  const float LOG2E = 1.4426950408889634f;

  const unsigned short* Qg = ws16 + Q_OFF  + (size_t)bh*SS*HDD;
  const unsigned short* Kg = ws16 + K_OFF  + (size_t)bh*SS*HDD;
  const unsigned short* Vg = ws16 + VT_OFF + (size_t)bh*HDD*SS;
  const float* maskB = mask + b*SS;

  // stage mask row * log2e (512 threads x float4 = 8KB)
  {
    float4 m4 = ((const float4*)maskB)[tid];
    m4.x*=LOG2E; m4.y*=LOG2E; m4.z*=LOG2E; m4.w*=LOG2E;
    *(float4*)&mlds[tid*4] = m4;
  }

  // resident Q fragments: B-operand (n=q=l15, k=d=h2*32+quad*8+j)
  bf16x8 aq[2];
  #pragma unroll
  for (int h2 = 0; h2 < 2; h2++)
    aq[h2] = *(const bf16x8*)(Qg + (size_t)(q0 + l15)*HDD + h2*32 + quad*8);

  // staging role split: waves 0-3 stage K (32 x 128B), waves 4-7 stage V (64 x 64B).
  // K source col pre-XOR-swizzled so linear dest yields LDS[kt][col ^ ((kt&7)<<4)].
  const unsigned short* sSrc;
  unsigned short* sDst;
  int sAdv;
  if (tid < 256){
    const int kr = tid >> 3, kp = tid & 7;
    sSrc = Kg + (size_t)kr*HDD + ((((kp*16) ^ ((kr&7)<<4)))>>1);
    sDst = &kb[0][0] + tid*8;                // 16B per thread, linear
    sAdv = 32*HDD;
  } else {
    const int t = tid - 256;
    const int vr = t >> 2, vp = t & 3;
    sSrc = Vg + (size_t)vr*SS + vp*8;
    sDst = &vb[0][0] + t*8;
    sAdv = 32;
  }
  unsigned short* pw = &pb[wave][0];

  f32x4 O[4] = {};               // O^T: elem (d=dg*16+quad*4+r, q=l15)
  float lacc = 0.f;

  // prologue: stage chunk 0 into buffer 0 (syncthreads drains vmcnt)
  ld_g2l_16(sSrc, sDst);
  const unsigned short* sp = sSrc + sAdv;
  __syncthreads();

  #pragma unroll 2
  for (int ch = 0; ch < 64; ++ch){
    const int cur = ch & 1;
    const int ktb = ch*32;
    if (ch < 63){                // issue next-chunk stage BEFORE compute (overlap)
      ld_g2l_16(sp, sDst + (cur^1)*2048);
      sp += sAdv;
    }
    const unsigned short* kcur = &kb[cur][0];
    const unsigned short* vcur = &vb[cur][0];

    // K fragments: A-operand (m=kt=fi*16+l15, k=d), swizzled read (conflict-free)
    bf16x8 ka[2][2];
    #pragma unroll
    for (int fi = 0; fi < 2; fi++)
      #pragma unroll
      for (int h2 = 0; h2 < 2; h2++){
        const int colb = (h2*64 + quad*16) ^ ((l15 & 7) << 4);
        ka[fi][h2] = *(const bf16x8*)&kcur[(fi*16 + l15)*64 + (colb>>1)];
      }

    // S^T = K·Q^T with C init = mask*log2e -> p = exp2(st) -> P^T to LDS
    #pragma unroll
    for (int fi = 0; fi < 2; fi++){
      f32x4 st = *(const f32x4*)&mlds[ktb + fi*16 + quad*4];  // same-addr broadcast
      st = __builtin_amdgcn_mfma_f32_16x16x32_bf16(ka[fi][0], aq[0], st, 0,0,0);
      st = __builtin_amdgcn_mfma_f32_16x16x32_bf16(ka[fi][1], aq[1], st, 0,0,0);
      f32x4 p;
      #pragma unroll
      for (int r = 0; r < 4; r++) p[r] = __builtin_amdgcn_exp2f(st[r]);
      lacc += (p[0] + p[1]) + (p[2] + p[3]);
      uint2 w; w.x = pk2bf(p[0], p[1]); w.y = pk2bf(p[2], p[3]);
      *(uint2*)&pw[l15*ST_P + fi*16 + quad*4] = w;
    }

    // V^T fragments: A-operand (m=d=dg*16+l15, k=kt=quad*8+j), 64B rows
    bf16x8 va[4];
    #pragma unroll
    for (int dg = 0; dg < 4; dg++)
      va[dg] = *(const bf16x8*)&vcur[(dg*16 + l15)*32 + quad*8];

    // O^T += V^T · P^T  (intra-wave LDS round-trip, wave-ordered, no barrier)
    {
      bf16x8 bp = *(const bf16x8*)&pw[l15*ST_P + quad*8];
      #pragma unroll
      for (int dg = 0; dg < 4; dg++)
        O[dg] = __builtin_amdgcn_mfma_f32_16x16x32_bf16(va[dg], bp, O[dg], 0,0,0);
    }

    __syncthreads();   // all waves done reading cur; next-chunk stage drained
  }

  // row sum: reduce lacc across quads (lanes with same l15 share q)
  float lq = lacc;
  lq += __shfl_xor(lq, 16);
  lq += __shfl_xor(lq, 32);
  const float inv = 1.0f / lq;

  // epilogue: scale by 1/l, write ctx [B,S,H] fp32 as float4 per dg
  float* op = out + ((size_t)b*SS + q0 + l15)*HH + h*HDD + quad*4;
  #pragma unroll
  for (int dg = 0; dg < 4; dg++){
    f32x4 v = O[dg];
    float4 o; o.x = v[0]*inv; o.y = v[1]*inv; o.z = v[2]*inv; o.w = v[3]*inv;
    *(float4*)(op + dg*16) = o;
  }
}

extern "C" void kernel_launch(void* const* d_in, const int* in_sizes, int n_in,
                              void* d_out, int out_size, void* d_ws, size_t ws_size,
                              hipStream_t stream){
  const float* hs   = (const float*)d_in[0];
  const float* mask = (const float*)d_in[1];
  const float* Wq   = (const float*)d_in[2];
  const float* bq   = (const float*)d_in[3];
  const float* Wk   = (const float*)d_in[4];
  const float* bk   = (const float*)d_in[5];
  const float* Wv   = (const float*)d_in[6];
  const float* bv   = (const float*)d_in[7];
  const float* qe   = (const float*)d_in[8];
  const float* ke   = (const float*)d_in[9];
  const float* ve   = (const float*)d_in[10];
  const int*   idx  = (const int*)d_in[11];
  unsigned short* ws16 = (unsigned short*)d_ws;
  float* out = (float*)d_out;

  convert_all<<<8192 + 768, 256, 0, stream>>>(hs, ws16 + XB_OFF, Wq, Wk, Wv, ws16 + WT_OFF);

  dim3 g2(M_TOT/128, HH/128, 3);
  qkv_gemm<<<g2, 256, 0, stream>>>(ws16, ws16, bq, bk, bv, qe, ke, ve, idx);

  attn_mfma<<<BB*NHH*SS/128, 512, 0, stream>>>(ws16, mask, out);
}

// Round 8
// 301.455 us; speedup vs baseline: 1.0563x; 1.0563x over previous
//
#include <hip/hip_runtime.h>
#include <hip/hip_bf16.h>
#include <stdint.h>

#define BB 4
#define SS 2048
#define HH 1024
#define NHH 16
#define HDD 64
#define M_TOT (BB*SS)          // 8192

// workspace layout (ushort/bf16 element offsets)
#define XB_OFF 0                              // hidden bf16 [8192][1024]
#define WT_OFF (M_TOT*HH)                     // Wq^T,Wk^T,Wv^T bf16 [3][N=1024][K=1024]
#define Q_OFF  (WT_OFF + 3*HH*HH)             // Q  [B][NH][S][HD]  (pre-scaled by 0.125*log2e!)
#define K_OFF  (Q_OFF + BB*NHH*SS*HDD)        // K  [B][NH][S][HD]
#define VT_OFF (K_OFF + BB*NHH*SS*HDD)        // Vt [B][NH][HD][S]  (transposed)

typedef short bf16x8 __attribute__((ext_vector_type(8)));
typedef float f32x4  __attribute__((ext_vector_type(4)));

__device__ inline unsigned short f2bf(float f){
  unsigned u = __float_as_uint(f);
  u += 0x7fffu + ((u >> 16) & 1u);   // RNE
  return (unsigned short)(u >> 16);
}
__device__ inline unsigned pk2bf(float lo, float hi){
  float2 t; t.x = lo; t.y = hi;
  __hip_bfloat162 h = __float22bfloat162_rn(t);
  return *(unsigned*)&h;
}

// async global->LDS, 16B per lane
__device__ __forceinline__ void ld_g2l_16(const unsigned short* g, unsigned short* l){
  __builtin_amdgcn_global_load_lds(
      (const __attribute__((address_space(1))) void*)g,
      (__attribute__((address_space(3))) void*)l, 16, 0, 0);
}

// ---------------- kernel 1: fused X->bf16 + W->WT bf16 (one launch) ----------------
__global__ void convert_all(const float* __restrict__ hs, unsigned short* __restrict__ xb,
                            const float* __restrict__ wq, const float* __restrict__ wk,
                            const float* __restrict__ wv, unsigned short* __restrict__ wt){
  __shared__ unsigned short t[64][65];
  const int tid = threadIdx.x;
  if (blockIdx.x < 8192){
    const int i = blockIdx.x*256 + tid;
    float4 v = ((const float4*)hs)[i];
    ushort4 o;
    o.x = f2bf(v.x); o.y = f2bf(v.y); o.z = f2bf(v.z); o.w = f2bf(v.w);
    ((ushort4*)xb)[i] = o;
    return;
  }
  const int wtb = blockIdx.x - 8192;
  const int z   = wtb >> 8;              // 256 tiles per z
  const int rem = wtb & 255;
  const int kb  = (rem & 15)*64, nb = (rem >> 4)*64;
  const float* W = (z==0) ? wq : ((z==1) ? wk : wv);
  unsigned short* WT = wt + z*HH*HH;
  #pragma unroll
  for (int i = 0; i < 16; i++){
    const int idx = i*256 + tid;
    const int r = idx >> 6, c = idx & 63;
    t[r][c] = f2bf(W[(kb + r)*HH + nb + c]);
  }
  __syncthreads();
  #pragma unroll
  for (int i = 0; i < 16; i++){
    const int idx = i*256 + tid;
    const int n = idx >> 6, k = idx & 63;
    WT[(nb + n)*HH + kb + k] = t[k][n];
  }
}

// ---------------- kernel 2: QKV projection GEMM ----------------
// R8: LDS-intensity restructure. R7 analysis: per-wave 64x64 = 512 B LDS-read per
// MFMA -> ~31us pure-LDS floor; kernel is LDS-BW structural, not occupancy-tunable.
// New geometry: block 256x128 tile, 4 waves (2M x 2N), PER-WAVE 128x64 (acc[8][4],
// 12 ds_read_b128 per 32 MFMA = 384 B/MFMA, staged bytes per MFMA halved).
// Schedule = R5's proven one, unchanged: 3-buffer, depth-2 prefetch, counted
// vmcnt(6) (6 loads/thread/iter: 4 A-chunks + 2 B-chunks), raw s_barrier, LDS XOR
// swizzle via pre-swizzled global source (bank conflicts measured 0 in R5).
// LDS 72KB -> 2 blocks/CU; target total regs <=256 -> 8 waves/CU.
// z in {0,1}: swapped MFMA -> lane holds 4 consecutive d -> ushort4 stores.
// z==2 (V^T): normal MFMA -> lane holds 4 consecutive s -> ushort4 stores.
__global__ __launch_bounds__(256) void qkv_gemm(
    const unsigned short* __restrict__ ws16, unsigned short* __restrict__ wsq,
    const float* __restrict__ bq, const float* __restrict__ bk, const float* __restrict__ bv,
    const float* __restrict__ qe, const float* __restrict__ ke, const float* __restrict__ ve,
    const int* __restrict__ idxp){
  __shared__ unsigned short al[3*256*32];   // 3 x 16KB  (A: 256 rows x 32 k)
  __shared__ unsigned short bl[3*128*32];   // 3 x 8KB   (B: 128 rows x 32 k)

  const unsigned short* Xb = ws16 + XB_OFF;
  const int z = blockIdx.z;
  const unsigned short* Wt = ws16 + WT_OFF + z*HH*HH;
  const float* bias = (z==0) ? bq : ((z==1) ? bk : bv);
  const float* emb  = (z==0) ? qe : ((z==1) ? ke : ve);

  const int tid  = threadIdx.x;
  const int wv   = tid >> 6;
  const int ln   = tid & 63;
  const int quad = ln >> 4;
  const int l15  = ln & 15;
  const int m0 = blockIdx.x * 256;
  const int n0 = blockIdx.y * 128;
  const int wm = wv & 1, wn = wv >> 1;       // wave tile: rows wm*128, cols wn*64
  const int swz = (l15 >> 1) & 3;            // read-side 16B-col XOR (R5-verified)

  // staging: thread t stages A rows {t>>2 + c*64, c<4} and B rows {t>>2 + c*64, c<2},
  // 16B piece (t&3). Source piece pre-XOR-swizzled by ((row>>1)&3) == ((t>>3)&3)
  // (row = t>>2 + c*64; c*64 is 0 mod 4 after >>1). Dest is lane-linear per wave:
  // chunk base + wv*512 (+ lane*16B by HW).
  const int sk  = (((tid & 3) ^ ((tid >> 3) & 3))) * 8;
  const int r0  = tid >> 2;
  const unsigned short* gA0 = &Xb[(size_t)(m0 + r0      )*HH + sk];
  const unsigned short* gA1 = &Xb[(size_t)(m0 + r0 +  64)*HH + sk];
  const unsigned short* gA2 = &Xb[(size_t)(m0 + r0 + 128)*HH + sk];
  const unsigned short* gA3 = &Xb[(size_t)(m0 + r0 + 192)*HH + sk];
  const unsigned short* gB0 = &Wt[(size_t)(n0 + r0      )*HH + sk];
  const unsigned short* gB1 = &Wt[(size_t)(n0 + r0 +  64)*HH + sk];
  unsigned short* aD = &al[wv*512];          // + c*2048 + SB*8192
  unsigned short* bD = &bl[wv*512];          // + c*2048 + SB*4096

  f32x4 acc[8][4] = {};

  // prologue: stage k=0 -> buf0, k=1 -> buf1 (12 loads in flight)
  ld_g2l_16(gA0,      aD);        ld_g2l_16(gA1,      aD + 2048);
  ld_g2l_16(gA2,      aD + 4096); ld_g2l_16(gA3,      aD + 6144);
  ld_g2l_16(gB0,      bD);        ld_g2l_16(gB1,      bD + 2048);
  ld_g2l_16(gA0 + 32, aD + 8192);        ld_g2l_16(gA1 + 32, aD + 8192 + 2048);
  ld_g2l_16(gA2 + 32, aD + 8192 + 4096); ld_g2l_16(gA3 + 32, aD + 8192 + 6144);
  ld_g2l_16(gB0 + 32, bD + 4096);        ld_g2l_16(gB1 + 32, bD + 4096 + 2048);

#define K_ITER(K, CUR, SB, DO_STAGE, VM)                                      \
  {                                                                           \
    asm volatile("s_waitcnt vmcnt(" #VM ")" ::: "memory");                    \
    __builtin_amdgcn_s_barrier();                                             \
    if (DO_STAGE){                                                            \
      const int ko = ((K) + 2) * 32;                                          \
      ld_g2l_16(gA0 + ko, aD + (SB)*8192);                                    \
      ld_g2l_16(gA1 + ko, aD + (SB)*8192 + 2048);                             \
      ld_g2l_16(gA2 + ko, aD + (SB)*8192 + 4096);                             \
      ld_g2l_16(gA3 + ko, aD + (SB)*8192 + 6144);                             \
      ld_g2l_16(gB0 + ko, bD + (SB)*4096);                                    \
      ld_g2l_16(gB1 + ko, bD + (SB)*4096 + 2048);                             \
    }                                                                         \
    const unsigned short* alc = &al[(CUR)*8192];                              \
    const unsigned short* blc = &bl[(CUR)*4096];                              \
    bf16x8 af[8], bf[4];                                                      \
    _Pragma("unroll")                                                         \
    for (int i = 0; i < 8; i++)                                               \
      af[i] = *(const bf16x8*)&alc[(wm*128 + i*16 + l15)*32 + (quad ^ swz)*8];\
    _Pragma("unroll")                                                         \
    for (int i = 0; i < 4; i++)                                               \
      bf[i] = *(const bf16x8*)&blc[(wn*64 + i*16 + l15)*32 + (quad ^ swz)*8]; \
    if (z == 2){                                                              \
      _Pragma("unroll")                                                       \
      for (int mi = 0; mi < 8; mi++)                                          \
        _Pragma("unroll")                                                     \
        for (int ni = 0; ni < 4; ni++)                                        \
          acc[mi][ni] = __builtin_amdgcn_mfma_f32_16x16x32_bf16(af[mi], bf[ni], acc[mi][ni], 0, 0, 0); \
    } else {                                                                  \
      _Pragma("unroll")                                                       \
      for (int mi = 0; mi < 8; mi++)                                          \
        _Pragma("unroll")                                                     \
        for (int ni = 0; ni < 4; ni++)                                        \
          acc[mi][ni] = __builtin_amdgcn_mfma_f32_16x16x32_bf16(bf[ni], af[mi], acc[mi][ni], 0, 0, 0); \
    }                                                                         \
  }

  for (int k = 0; k < 30; k += 3){
    K_ITER(k,     0, 2, 1, 6)
    K_ITER(k + 1, 1, 0, 1, 6)
    K_ITER(k + 2, 2, 1, 1, 6)
  }
  K_ITER(30, 0, 0, 0, 6)   // no stage; wait stage(30)
  K_ITER(31, 1, 0, 0, 0)   // no stage; drain stage(31)
#undef K_ITER

  const int index = idxp[0];
  if (z == 2){
    // V^T: [bh][d][s], normal orientation: lane holds 4 consecutive s -> ushort4
    #pragma unroll
    for (int ni = 0; ni < 4; ni++){
      const int n = n0 + wn*64 + ni*16 + l15;
      const float biasv = bias[n] + emb[index*HH + n];
      const int h = n >> 6, d = n & 63;
      #pragma unroll
      for (int mi = 0; mi < 8; mi++){
        const int g  = m0 + wm*128 + mi*16 + quad*4;  // 4 consecutive s (4-aligned)
        const int b_ = g >> 11;
        const int s_ = g & (SS - 1);
        const int bh = b_*NHH + h;
        const f32x4 a = acc[mi][ni];
        ushort4 o;
        o.x = f2bf(a[0] + biasv); o.y = f2bf(a[1] + biasv);
        o.z = f2bf(a[2] + biasv); o.w = f2bf(a[3] + biasv);
        *(ushort4*)&wsq[VT_OFF + (size_t)(bh*HDD + d)*SS + s_] = o;
      }
    }
  } else {
    // Q/K: [bh][s][d], swapped: lane holds 4 consecutive d at fixed s -> ushort4
    const float oscale = (z==0) ? 0.18033688011112042f : 1.0f;  // 0.125*log2(e)
    const size_t obase = (z==0) ? (size_t)Q_OFF : (size_t)K_OFF;
    #pragma unroll
    for (int mi = 0; mi < 8; mi++){
      const int sg = m0 + wm*128 + mi*16 + l15;       // s-row (from B-operand col)
      const int b_ = sg >> 11;
      const int s_ = sg & (SS - 1);
      #pragma unroll
      for (int ni = 0; ni < 4; ni++){
        const int nb = n0 + wn*64 + ni*16 + quad*4;   // 4 consecutive n (4-aligned)
        const int h  = nb >> 6, d0 = nb & 63;         // no h-cross (d0 % 4 == 0)
        const int bh = b_*NHH + h;
        const float4 b4 = *(const float4*)&bias[nb];
        const float4 e4 = *(const float4*)&emb[index*HH + nb];
        const f32x4 a = acc[mi][ni];
        ushort4 o;
        o.x = f2bf((a[0] + b4.x + e4.x) * oscale);
        o.y = f2bf((a[1] + b4.y + e4.y) * oscale);
        o.z = f2bf((a[2] + b4.z + e4.z) * oscale);
        o.w = f2bf((a[3] + b4.w + e4.w) * oscale);
        *(ushort4*)&wsq[obase + (size_t)(bh*SS + s_)*HDD + d0] = o;
      }
    }
  }
}

// ---------------- kernel 3: flash attention, 16q/wave, 8-wave blocks ----------------
// (R2 known-good version: 112 µs measured.)
#define ST_P 40   // P^T row stride (shorts): 80B
__global__ __launch_bounds__(512, 6) void attn_mfma(
    const unsigned short* __restrict__ ws16,
    const float* __restrict__ mask, float* __restrict__ out){
  __shared__ __align__(16) unsigned short kb[2][32*64];   // [kt][d], swizzled, 2x4KB
  __shared__ __align__(16) unsigned short vb[2][64*32];   // [d][kt], linear,   2x4KB
  __shared__ __align__(16) unsigned short pb[8][16*ST_P]; // per-wave P^T [q][kt], 10.24KB
  __shared__ __align__(16) float mlds[SS];                // mask row * log2e, 8KB

  const int tid  = threadIdx.x;
  const int wave = tid >> 6;
  const int lane = tid & 63;
  const int quad = lane >> 4;
  const int l15  = lane & 15;

  // XCD-aware swizzle (bijective: 1024 % 8 == 0): each head's 16 blocks on one XCD.
  const int bid  = (blockIdx.x & 7)*128 + (blockIdx.x >> 3);
  const int qb   = bid & 15;                 // 16 q-blocks of 128 rows per bh
  const int bh   = bid >> 4;
  const int b    = bh >> 4, h = bh & 15;
  const int q0   = qb*128 + wave*16;         // this wave's first q row
  const float LOG2E = 1.4426950408889634f;

  const unsigned short* Qg = ws16 + Q_OFF  + (size_t)bh*SS*HDD;
  const unsigned short* Kg = ws16 + K_OFF  + (size_t)bh*SS*HDD;
  const unsigned short* Vg = ws16 + VT_OFF + (size_t)bh*HDD*SS;
  const float* maskB = mask + b*SS;

  // stage mask row * log2e (512 threads x float4 = 8KB)
  {
    float4 m4 = ((const float4*)maskB)[tid];
    m4.x*=LOG2E; m4.y*=LOG2E; m4.z*=LOG2E; m4.w*=LOG2E;
    *(float4*)&mlds[tid*4] = m4;
  }

  // resident Q fragments: B-operand (n=q=l15, k=d=h2*32+quad*8+j)
  bf16x8 aq[2];
  #pragma unroll
  for (int h2 = 0; h2 < 2; h2++)
    aq[h2] = *(const bf16x8*)(Qg + (size_t)(q0 + l15)*HDD + h2*32 + quad*8);

  // staging role split: waves 0-3 stage K (32 x 128B), waves 4-7 stage V (64 x 64B).
  // K source col pre-XOR-swizzled so linear dest yields LDS[kt][col ^ ((kt&7)<<4)].
  const unsigned short* sSrc;
  unsigned short* sDst;
  int sAdv;
  if (tid < 256){
    const int kr = tid >> 3, kp = tid & 7;
    sSrc = Kg + (size_t)kr*HDD + ((((kp*16) ^ ((kr&7)<<4)))>>1);
    sDst = &kb[0][0] + tid*8;                // 16B per thread, linear
    sAdv = 32*HDD;
  } else {
    const int t = tid - 256;
    const int vr = t >> 2, vp = t & 3;
    sSrc = Vg + (size_t)vr*SS + vp*8;
    sDst = &vb[0][0] + t*8;
    sAdv = 32;
  }
  unsigned short* pw = &pb[wave][0];

  f32x4 O[4] = {};               // O^T: elem (d=dg*16+quad*4+r, q=l15)
  float lacc = 0.f;

  // prologue: stage chunk 0 into buffer 0 (syncthreads drains vmcnt)
  ld_g2l_16(sSrc, sDst);
  const unsigned short* sp = sSrc + sAdv;
  __syncthreads();

  #pragma unroll 2
  for (int ch = 0; ch < 64; ++ch){
    const int cur = ch & 1;
    const int ktb = ch*32;
    if (ch < 63){                // issue next-chunk stage BEFORE compute (overlap)
      ld_g2l_16(sp, sDst + (cur^1)*2048);
      sp += sAdv;
    }
    const unsigned short* kcur = &kb[cur][0];
    const unsigned short* vcur = &vb[cur][0];

    // K fragments: A-operand (m=kt=fi*16+l15, k=d), swizzled read (conflict-free)
    bf16x8 ka[2][2];
    #pragma unroll
    for (int fi = 0; fi < 2; fi++)
      #pragma unroll
      for (int h2 = 0; h2 < 2; h2++){
        const int colb = (h2*64 + quad*16) ^ ((l15 & 7) << 4);
        ka[fi][h2] = *(const bf16x8*)&kcur[(fi*16 + l15)*64 + (colb>>1)];
      }

    // S^T = K·Q^T with C init = mask*log2e -> p = exp2(st) -> P^T to LDS
    #pragma unroll
    for (int fi = 0; fi < 2; fi++){
      f32x4 st = *(const f32x4*)&mlds[ktb + fi*16 + quad*4];  // same-addr broadcast
      st = __builtin_amdgcn_mfma_f32_16x16x32_bf16(ka[fi][0], aq[0], st, 0,0,0);
      st = __builtin_amdgcn_mfma_f32_16x16x32_bf16(ka[fi][1], aq[1], st, 0,0,0);
      f32x4 p;
      #pragma unroll
      for (int r = 0; r < 4; r++) p[r] = __builtin_amdgcn_exp2f(st[r]);
      lacc += (p[0] + p[1]) + (p[2] + p[3]);
      uint2 w; w.x = pk2bf(p[0], p[1]); w.y = pk2bf(p[2], p[3]);
      *(uint2*)&pw[l15*ST_P + fi*16 + quad*4] = w;
    }

    // V^T fragments: A-operand (m=d=dg*16+l15, k=kt=quad*8+j), 64B rows
    bf16x8 va[4];
    #pragma unroll
    for (int dg = 0; dg < 4; dg++)
      va[dg] = *(const bf16x8*)&vcur[(dg*16 + l15)*32 + quad*8];

    // O^T += V^T · P^T  (intra-wave LDS round-trip, wave-ordered, no barrier)
    {
      bf16x8 bp = *(const bf16x8*)&pw[l15*ST_P + quad*8];
      #pragma unroll
      for (int dg = 0; dg < 4; dg++)
        O[dg] = __builtin_amdgcn_mfma_f32_16x16x32_bf16(va[dg], bp, O[dg], 0,0,0);
    }

    __syncthreads();   // all waves done reading cur; next-chunk stage drained
  }

  // row sum: reduce lacc across quads (lanes with same l15 share q)
  float lq = lacc;
  lq += __shfl_xor(lq, 16);
  lq += __shfl_xor(lq, 32);
  const float inv = 1.0f / lq;

  // epilogue: scale by 1/l, write ctx [B,S,H] fp32 as float4 per dg
  float* op = out + ((size_t)b*SS + q0 + l15)*HH + h*HDD + quad*4;
  #pragma unroll
  for (int dg = 0; dg < 4; dg++){
    f32x4 v = O[dg];
    float4 o; o.x = v[0]*inv; o.y = v[1]*inv; o.z = v[2]*inv; o.w = v[3]*inv;
    *(float4*)(op + dg*16) = o;
  }
}

extern "C" void kernel_launch(void* const* d_in, const int* in_sizes, int n_in,
                              void* d_out, int out_size, void* d_ws, size_t ws_size,
                              hipStream_t stream){
  const float* hs   = (const float*)d_in[0];
  const float* mask = (const float*)d_in[1];
  const float* Wq   = (const float*)d_in[2];
  const float* bq   = (const float*)d_in[3];
  const float* Wk   = (const float*)d_in[4];
  const float* bk   = (const float*)d_in[5];
  const float* Wv   = (const float*)d_in[6];
  const float* bv   = (const float*)d_in[7];
  const float* qe   = (const float*)d_in[8];
  const float* ke   = (const float*)d_in[9];
  const float* ve   = (const float*)d_in[10];
  const int*   idx  = (const int*)d_in[11];
  unsigned short* ws16 = (unsigned short*)d_ws;
  float* out = (float*)d_out;

  convert_all<<<8192 + 768, 256, 0, stream>>>(hs, ws16 + XB_OFF, Wq, Wk, Wv, ws16 + WT_OFF);

  dim3 g2(M_TOT/256, HH/128, 3);
  qkv_gemm<<<g2, 256, 0, stream>>>(ws16, ws16, bq, bk, bv, qe, ke, ve, idx);

  attn_mfma<<<BB*NHH*SS/128, 512, 0, stream>>>(ws16, mask, out);
}

// Round 9
// 293.817 us; speedup vs baseline: 1.0838x; 1.0260x over previous
//
#include <hip/hip_runtime.h>
#include <hip/hip_bf16.h>
#include <stdint.h>

#define BB 4
#define SS 2048
#define HH 1024
#define NHH 16
#define HDD 64
#define M_TOT (BB*SS)          // 8192

// workspace layout (ushort/bf16 element offsets)
#define XB_OFF 0                              // hidden bf16 [8192][1024]
#define WT_OFF (M_TOT*HH)                     // Wq^T,Wk^T,Wv^T bf16 [3][N=1024][K=1024]
#define Q_OFF  (WT_OFF + 3*HH*HH)             // Q  [B][NH][S][HD]  (pre-scaled by 0.125*log2e!)
#define K_OFF  (Q_OFF + BB*NHH*SS*HDD)        // K  [B][NH][S][HD]
#define VT_OFF (K_OFF + BB*NHH*SS*HDD)        // Vt [B][NH][HD][S]  (transposed)

typedef short bf16x8 __attribute__((ext_vector_type(8)));
typedef float f32x4  __attribute__((ext_vector_type(4)));
typedef unsigned uint32x2 __attribute__((ext_vector_type(2)));

__device__ inline unsigned short f2bf(float f){
  unsigned u = __float_as_uint(f);
  u += 0x7fffu + ((u >> 16) & 1u);   // RNE
  return (unsigned short)(u >> 16);
}
__device__ inline unsigned pk2bf(float lo, float hi){
  float2 t; t.x = lo; t.y = hi;
  __hip_bfloat162 h = __float22bfloat162_rn(t);
  return *(unsigned*)&h;
}

// async global->LDS, 16B per lane
__device__ __forceinline__ void ld_g2l_16(const unsigned short* g, unsigned short* l){
  __builtin_amdgcn_global_load_lds(
      (const __attribute__((address_space(1))) void*)g,
      (__attribute__((address_space(3))) void*)l, 16, 0, 0);
}

// ---------------- kernel 1: fused X->bf16 + W->WT bf16 (one launch) ----------------
__global__ void convert_all(const float* __restrict__ hs, unsigned short* __restrict__ xb,
                            const float* __restrict__ wq, const float* __restrict__ wk,
                            const float* __restrict__ wv, unsigned short* __restrict__ wt){
  __shared__ unsigned short t[64][65];
  const int tid = threadIdx.x;
  if (blockIdx.x < 8192){
    const int i = blockIdx.x*256 + tid;
    float4 v = ((const float4*)hs)[i];
    ushort4 o;
    o.x = f2bf(v.x); o.y = f2bf(v.y); o.z = f2bf(v.z); o.w = f2bf(v.w);
    ((ushort4*)xb)[i] = o;
    return;
  }
  const int wtb = blockIdx.x - 8192;
  const int z   = wtb >> 8;              // 256 tiles per z
  const int rem = wtb & 255;
  const int kb  = (rem & 15)*64, nb = (rem >> 4)*64;
  const float* W = (z==0) ? wq : ((z==1) ? wk : wv);
  unsigned short* WT = wt + z*HH*HH;
  #pragma unroll
  for (int i = 0; i < 16; i++){
    const int idx = i*256 + tid;
    const int r = idx >> 6, c = idx & 63;
    t[r][c] = f2bf(W[(kb + r)*HH + nb + c]);
  }
  __syncthreads();
  #pragma unroll
  for (int i = 0; i < 16; i++){
    const int idx = i*256 + tid;
    const int n = idx >> 6, k = idx & 63;
    WT[(nb + n)*HH + kb + k] = t[k][n];
  }
}

// ---------------- kernel 2: QKV projection GEMM ----------------
// (R8 version, improved: fell below attn in top-5. Unchanged this round.)
__global__ __launch_bounds__(256) void qkv_gemm(
    const unsigned short* __restrict__ ws16, unsigned short* __restrict__ wsq,
    const float* __restrict__ bq, const float* __restrict__ bk, const float* __restrict__ bv,
    const float* __restrict__ qe, const float* __restrict__ ke, const float* __restrict__ ve,
    const int* __restrict__ idxp){
  __shared__ unsigned short al[3*256*32];   // 3 x 16KB  (A: 256 rows x 32 k)
  __shared__ unsigned short bl[3*128*32];   // 3 x 8KB   (B: 128 rows x 32 k)

  const unsigned short* Xb = ws16 + XB_OFF;
  const int z = blockIdx.z;
  const unsigned short* Wt = ws16 + WT_OFF + z*HH*HH;
  const float* bias = (z==0) ? bq : ((z==1) ? bk : bv);
  const float* emb  = (z==0) ? qe : ((z==1) ? ke : ve);

  const int tid  = threadIdx.x;
  const int wv   = tid >> 6;
  const int ln   = tid & 63;
  const int quad = ln >> 4;
  const int l15  = ln & 15;
  const int m0 = blockIdx.x * 256;
  const int n0 = blockIdx.y * 128;
  const int wm = wv & 1, wn = wv >> 1;       // wave tile: rows wm*128, cols wn*64
  const int swz = (l15 >> 1) & 3;            // read-side 16B-col XOR (R5-verified)

  const int sk  = (((tid & 3) ^ ((tid >> 3) & 3))) * 8;
  const int r0  = tid >> 2;
  const unsigned short* gA0 = &Xb[(size_t)(m0 + r0      )*HH + sk];
  const unsigned short* gA1 = &Xb[(size_t)(m0 + r0 +  64)*HH + sk];
  const unsigned short* gA2 = &Xb[(size_t)(m0 + r0 + 128)*HH + sk];
  const unsigned short* gA3 = &Xb[(size_t)(m0 + r0 + 192)*HH + sk];
  const unsigned short* gB0 = &Wt[(size_t)(n0 + r0      )*HH + sk];
  const unsigned short* gB1 = &Wt[(size_t)(n0 + r0 +  64)*HH + sk];
  unsigned short* aD = &al[wv*512];          // + c*2048 + SB*8192
  unsigned short* bD = &bl[wv*512];          // + c*2048 + SB*4096

  f32x4 acc[8][4] = {};

  // prologue: stage k=0 -> buf0, k=1 -> buf1 (12 loads in flight)
  ld_g2l_16(gA0,      aD);        ld_g2l_16(gA1,      aD + 2048);
  ld_g2l_16(gA2,      aD + 4096); ld_g2l_16(gA3,      aD + 6144);
  ld_g2l_16(gB0,      bD);        ld_g2l_16(gB1,      bD + 2048);
  ld_g2l_16(gA0 + 32, aD + 8192);        ld_g2l_16(gA1 + 32, aD + 8192 + 2048);
  ld_g2l_16(gA2 + 32, aD + 8192 + 4096); ld_g2l_16(gA3 + 32, aD + 8192 + 6144);
  ld_g2l_16(gB0 + 32, bD + 4096);        ld_g2l_16(gB1 + 32, bD + 4096 + 2048);

#define K_ITER(K, CUR, SB, DO_STAGE, VM)                                      \
  {                                                                           \
    asm volatile("s_waitcnt vmcnt(" #VM ")" ::: "memory");                    \
    __builtin_amdgcn_s_barrier();                                             \
    if (DO_STAGE){                                                            \
      const int ko = ((K) + 2) * 32;                                          \
      ld_g2l_16(gA0 + ko, aD + (SB)*8192);                                    \
      ld_g2l_16(gA1 + ko, aD + (SB)*8192 + 2048);                             \
      ld_g2l_16(gA2 + ko, aD + (SB)*8192 + 4096);                             \
      ld_g2l_16(gA3 + ko, aD + (SB)*8192 + 6144);                             \
      ld_g2l_16(gB0 + ko, bD + (SB)*4096);                                    \
      ld_g2l_16(gB1 + ko, bD + (SB)*4096 + 2048);                             \
    }                                                                         \
    const unsigned short* alc = &al[(CUR)*8192];                              \
    const unsigned short* blc = &bl[(CUR)*4096];                              \
    bf16x8 af[8], bf[4];                                                      \
    _Pragma("unroll")                                                         \
    for (int i = 0; i < 8; i++)                                               \
      af[i] = *(const bf16x8*)&alc[(wm*128 + i*16 + l15)*32 + (quad ^ swz)*8];\
    _Pragma("unroll")                                                         \
    for (int i = 0; i < 4; i++)                                               \
      bf[i] = *(const bf16x8*)&blc[(wn*64 + i*16 + l15)*32 + (quad ^ swz)*8]; \
    if (z == 2){                                                              \
      _Pragma("unroll")                                                       \
      for (int mi = 0; mi < 8; mi++)                                          \
        _Pragma("unroll")                                                     \
        for (int ni = 0; ni < 4; ni++)                                        \
          acc[mi][ni] = __builtin_amdgcn_mfma_f32_16x16x32_bf16(af[mi], bf[ni], acc[mi][ni], 0, 0, 0); \
    } else {                                                                  \
      _Pragma("unroll")                                                       \
      for (int mi = 0; mi < 8; mi++)                                          \
        _Pragma("unroll")                                                     \
        for (int ni = 0; ni < 4; ni++)                                        \
          acc[mi][ni] = __builtin_amdgcn_mfma_f32_16x16x32_bf16(bf[ni], af[mi], acc[mi][ni], 0, 0, 0); \
    }                                                                         \
  }

  for (int k = 0; k < 30; k += 3){
    K_ITER(k,     0, 2, 1, 6)
    K_ITER(k + 1, 1, 0, 1, 6)
    K_ITER(k + 2, 2, 1, 1, 6)
  }
  K_ITER(30, 0, 0, 0, 6)   // no stage; wait stage(30)
  K_ITER(31, 1, 0, 0, 0)   // no stage; drain stage(31)
#undef K_ITER

  const int index = idxp[0];
  if (z == 2){
    // V^T: [bh][d][s], normal orientation: lane holds 4 consecutive s -> ushort4
    #pragma unroll
    for (int ni = 0; ni < 4; ni++){
      const int n = n0 + wn*64 + ni*16 + l15;
      const float biasv = bias[n] + emb[index*HH + n];
      const int h = n >> 6, d = n & 63;
      #pragma unroll
      for (int mi = 0; mi < 8; mi++){
        const int g  = m0 + wm*128 + mi*16 + quad*4;  // 4 consecutive s (4-aligned)
        const int b_ = g >> 11;
        const int s_ = g & (SS - 1);
        const int bh = b_*NHH + h;
        const f32x4 a = acc[mi][ni];
        ushort4 o;
        o.x = f2bf(a[0] + biasv); o.y = f2bf(a[1] + biasv);
        o.z = f2bf(a[2] + biasv); o.w = f2bf(a[3] + biasv);
        *(ushort4*)&wsq[VT_OFF + (size_t)(bh*HDD + d)*SS + s_] = o;
      }
    }
  } else {
    // Q/K: [bh][s][d], swapped: lane holds 4 consecutive d at fixed s -> ushort4
    const float oscale = (z==0) ? 0.18033688011112042f : 1.0f;  // 0.125*log2(e)
    const size_t obase = (z==0) ? (size_t)Q_OFF : (size_t)K_OFF;
    #pragma unroll
    for (int mi = 0; mi < 8; mi++){
      const int sg = m0 + wm*128 + mi*16 + l15;       // s-row (from B-operand col)
      const int b_ = sg >> 11;
      const int s_ = sg & (SS - 1);
      #pragma unroll
      for (int ni = 0; ni < 4; ni++){
        const int nb = n0 + wn*64 + ni*16 + quad*4;   // 4 consecutive n (4-aligned)
        const int h  = nb >> 6, d0 = nb & 63;         // no h-cross (d0 % 4 == 0)
        const int bh = b_*NHH + h;
        const float4 b4 = *(const float4*)&bias[nb];
        const float4 e4 = *(const float4*)&emb[index*HH + nb];
        const f32x4 a = acc[mi][ni];
        ushort4 o;
        o.x = f2bf((a[0] + b4.x + e4.x) * oscale);
        o.y = f2bf((a[1] + b4.y + e4.y) * oscale);
        o.z = f2bf((a[2] + b4.z + e4.z) * oscale);
        o.w = f2bf((a[3] + b4.w + e4.w) * oscale);
        *(ushort4*)&wsq[obase + (size_t)(bh*SS + s_)*HDD + d0] = o;
      }
    }
  }
}

// ---------------- kernel 3: flash attention, 16q/wave, 8-wave blocks ----------------
// R9: attn is LDS-BW-bound (R8 analysis: ~11KB LDS/chunk/wave ≈ 85µs of the 112µs).
// T12: P redistribution moved from LDS round-trip (pb write uint2 x2 + read b128,
// 10.24KB buffer) to 4 VALU permlane ops. Derivation: after swapped QK^T, lane
// (quad,l15) holds u32 pk-pairs A0/A1 (fi=0: c=2quad,2quad+1) and B0/B1 (fi=1:
// c=8+2quad,+1) where c=kt/2. PV B-operand needs lane quad' to hold c={4q'..4q'+3}.
//   swap32(A0,B0) -> X0=(A0.q01, B0.q01<-lanes0-31), X1=(A0.q23, B0.q23)
//   swap16(X0,X1) -> Y0=(X0.q0,X1.q0,X0.q2,X1.q2)=w0, Y1=w2;  same on (A1,B1)->w1,w3.
// Bit-identical numerics. LDS/chunk 11->9KB; serial S->LDS->PV link removed.
#define LOG2E_F 1.4426950408889634f
__global__ __launch_bounds__(512, 6) void attn_mfma(
    const unsigned short* __restrict__ ws16,
    const float* __restrict__ mask, float* __restrict__ out){
  __shared__ __align__(16) unsigned short kb[2][32*64];   // [kt][d], swizzled, 2x4KB
  __shared__ __align__(16) unsigned short vb[2][64*32];   // [d][kt], linear,   2x4KB
  __shared__ __align__(16) float mlds[SS];                // mask row * log2e, 8KB

  const int tid  = threadIdx.x;
  const int wave = tid >> 6;
  const int lane = tid & 63;
  const int quad = lane >> 4;
  const int l15  = lane & 15;

  // XCD-aware swizzle (bijective: 1024 % 8 == 0): each head's 16 blocks on one XCD.
  const int bid  = (blockIdx.x & 7)*128 + (blockIdx.x >> 3);
  const int qb   = bid & 15;                 // 16 q-blocks of 128 rows per bh
  const int bh   = bid >> 4;
  const int b    = bh >> 4, h = bh & 15;
  const int q0   = qb*128 + wave*16;         // this wave's first q row

  const unsigned short* Qg = ws16 + Q_OFF  + (size_t)bh*SS*HDD;
  const unsigned short* Kg = ws16 + K_OFF  + (size_t)bh*SS*HDD;
  const unsigned short* Vg = ws16 + VT_OFF + (size_t)bh*HDD*SS;
  const float* maskB = mask + b*SS;

  // stage mask row * log2e (512 threads x float4 = 8KB)
  {
    float4 m4 = ((const float4*)maskB)[tid];
    m4.x*=LOG2E_F; m4.y*=LOG2E_F; m4.z*=LOG2E_F; m4.w*=LOG2E_F;
    *(float4*)&mlds[tid*4] = m4;
  }

  // resident Q fragments: B-operand (n=q=l15, k=d=h2*32+quad*8+j)
  bf16x8 aq[2];
  #pragma unroll
  for (int h2 = 0; h2 < 2; h2++)
    aq[h2] = *(const bf16x8*)(Qg + (size_t)(q0 + l15)*HDD + h2*32 + quad*8);

  // staging role split: waves 0-3 stage K (32 x 128B), waves 4-7 stage V (64 x 64B).
  // K source col pre-XOR-swizzled so linear dest yields LDS[kt][col ^ ((kt&7)<<4)].
  const unsigned short* sSrc;
  unsigned short* sDst;
  int sAdv;
  if (tid < 256){
    const int kr = tid >> 3, kp = tid & 7;
    sSrc = Kg + (size_t)kr*HDD + ((((kp*16) ^ ((kr&7)<<4)))>>1);
    sDst = &kb[0][0] + tid*8;                // 16B per thread, linear
    sAdv = 32*HDD;
  } else {
    const int t = tid - 256;
    const int vr = t >> 2, vp = t & 3;
    sSrc = Vg + (size_t)vr*SS + vp*8;
    sDst = &vb[0][0] + t*8;
    sAdv = 32;
  }

  f32x4 O[4] = {};               // O^T: elem (d=dg*16+quad*4+r, q=l15)
  float lacc = 0.f;

  // prologue: stage chunk 0 into buffer 0 (syncthreads drains vmcnt)
  ld_g2l_16(sSrc, sDst);
  const unsigned short* sp = sSrc + sAdv;
  __syncthreads();

  #pragma unroll 2
  for (int ch = 0; ch < 64; ++ch){
    const int cur = ch & 1;
    const int ktb = ch*32;
    if (ch < 63){                // issue next-chunk stage BEFORE compute (overlap)
      ld_g2l_16(sp, sDst + (cur^1)*2048);
      sp += sAdv;
    }
    const unsigned short* kcur = &kb[cur][0];
    const unsigned short* vcur = &vb[cur][0];

    // K fragments: A-operand (m=kt=fi*16+l15, k=d), swizzled read (conflict-free)
    bf16x8 ka[2][2];
    #pragma unroll
    for (int fi = 0; fi < 2; fi++)
      #pragma unroll
      for (int h2 = 0; h2 < 2; h2++){
        const int colb = (h2*64 + quad*16) ^ ((l15 & 7) << 4);
        ka[fi][h2] = *(const bf16x8*)&kcur[(fi*16 + l15)*64 + (colb>>1)];
      }

    // S^T = K·Q^T with C init = mask*log2e -> p = exp2(st) -> pk to u32 pairs
    unsigned A0, A1, B0, B1;
    {
      f32x4 st = *(const f32x4*)&mlds[ktb + quad*4];           // fi=0
      st = __builtin_amdgcn_mfma_f32_16x16x32_bf16(ka[0][0], aq[0], st, 0,0,0);
      st = __builtin_amdgcn_mfma_f32_16x16x32_bf16(ka[0][1], aq[1], st, 0,0,0);
      f32x4 p;
      #pragma unroll
      for (int r = 0; r < 4; r++) p[r] = __builtin_amdgcn_exp2f(st[r]);
      lacc += (p[0] + p[1]) + (p[2] + p[3]);
      A0 = pk2bf(p[0], p[1]); A1 = pk2bf(p[2], p[3]);
    }
    {
      f32x4 st = *(const f32x4*)&mlds[ktb + 16 + quad*4];      // fi=1
      st = __builtin_amdgcn_mfma_f32_16x16x32_bf16(ka[1][0], aq[0], st, 0,0,0);
      st = __builtin_amdgcn_mfma_f32_16x16x32_bf16(ka[1][1], aq[1], st, 0,0,0);
      f32x4 p;
      #pragma unroll
      for (int r = 0; r < 4; r++) p[r] = __builtin_amdgcn_exp2f(st[r]);
      lacc += (p[0] + p[1]) + (p[2] + p[3]);
      B0 = pk2bf(p[0], p[1]); B1 = pk2bf(p[2], p[3]);
    }

    // in-register P redistribution: 2x permlane32_swap + 2x permlane16_swap (VALU)
    uint32x2 x  = __builtin_amdgcn_permlane32_swap(A0, B0, 0, 0);
    uint32x2 y  = __builtin_amdgcn_permlane32_swap(A1, B1, 0, 0);
    uint32x2 w02 = __builtin_amdgcn_permlane16_swap(x[0], x[1], 0, 0); // w0, w2
    uint32x2 w13 = __builtin_amdgcn_permlane16_swap(y[0], y[1], 0, 0); // w1, w3
    union { unsigned u[4]; bf16x8 v; } bpu;
    bpu.u[0] = w02[0]; bpu.u[1] = w13[0]; bpu.u[2] = w02[1]; bpu.u[3] = w13[1];
    const bf16x8 bp = bpu.v;

    // V^T fragments: A-operand (m=d=dg*16+l15, k=kt=quad*8+j), 64B rows
    bf16x8 va[4];
    #pragma unroll
    for (int dg = 0; dg < 4; dg++)
      va[dg] = *(const bf16x8*)&vcur[(dg*16 + l15)*32 + quad*8];

    // O^T += V^T · P^T  (P entirely in registers — no LDS round-trip)
    #pragma unroll
    for (int dg = 0; dg < 4; dg++)
      O[dg] = __builtin_amdgcn_mfma_f32_16x16x32_bf16(va[dg], bp, O[dg], 0,0,0);

    __syncthreads();   // all waves done reading cur; next-chunk stage drained
  }

  // row sum: reduce lacc across quads (lanes with same l15 share q)
  float lq = lacc;
  lq += __shfl_xor(lq, 16);
  lq += __shfl_xor(lq, 32);
  const float inv = 1.0f / lq;

  // epilogue: scale by 1/l, write ctx [B,S,H] fp32 as float4 per dg
  float* op = out + ((size_t)b*SS + q0 + l15)*HH + h*HDD + quad*4;
  #pragma unroll
  for (int dg = 0; dg < 4; dg++){
    f32x4 v = O[dg];
    float4 o; o.x = v[0]*inv; o.y = v[1]*inv; o.z = v[2]*inv; o.w = v[3]*inv;
    *(float4*)(op + dg*16) = o;
  }
}

extern "C" void kernel_launch(void* const* d_in, const int* in_sizes, int n_in,
                              void* d_out, int out_size, void* d_ws, size_t ws_size,
                              hipStream_t stream){
  const float* hs   = (const float*)d_in[0];
  const float* mask = (const float*)d_in[1];
  const float* Wq   = (const float*)d_in[2];
  const float* bq   = (const float*)d_in[3];
  const float* Wk   = (const float*)d_in[4];
  const float* bk   = (const float*)d_in[5];
  const float* Wv   = (const float*)d_in[6];
  const float* bv   = (const float*)d_in[7];
  const float* qe   = (const float*)d_in[8];
  const float* ke   = (const float*)d_in[9];
  const float* ve   = (const float*)d_in[10];
  const int*   idx  = (const int*)d_in[11];
  unsigned short* ws16 = (unsigned short*)d_ws;
  float* out = (float*)d_out;

  convert_all<<<8192 + 768, 256, 0, stream>>>(hs, ws16 + XB_OFF, Wq, Wk, Wv, ws16 + WT_OFF);

  dim3 g2(M_TOT/256, HH/128, 3);
  qkv_gemm<<<g2, 256, 0, stream>>>(ws16, ws16, bq, bk, bv, qe, ke, ve, idx);

  attn_mfma<<<BB*NHH*SS/128, 512, 0, stream>>>(ws16, mask, out);
}

// Round 10
// 281.663 us; speedup vs baseline: 1.1305x; 1.0432x over previous
//
#include <hip/hip_runtime.h>
#include <hip/hip_bf16.h>
#include <stdint.h>

#define BB 4
#define SS 2048
#define HH 1024
#define NHH 16
#define HDD 64
#define M_TOT (BB*SS)          // 8192

// workspace layout (ushort/bf16 element offsets)
#define XB_OFF 0                              // hidden bf16 [8192][1024]
#define WT_OFF (M_TOT*HH)                     // Wq^T,Wk^T,Wv^T bf16 [3][N=1024][K=1024]
#define Q_OFF  (WT_OFF + 3*HH*HH)             // Q  [B][NH][S][HD]  (pre-scaled by 0.125*log2e!)
#define K_OFF  (Q_OFF + BB*NHH*SS*HDD)        // K  [B][NH][S][HD]
#define VT_OFF (K_OFF + BB*NHH*SS*HDD)        // Vt [B][NH][HD][S]  (transposed)

typedef short bf16x8 __attribute__((ext_vector_type(8)));
typedef float f32x4  __attribute__((ext_vector_type(4)));
typedef unsigned uint32x2 __attribute__((ext_vector_type(2)));

__device__ inline unsigned short f2bf(float f){
  unsigned u = __float_as_uint(f);
  u += 0x7fffu + ((u >> 16) & 1u);   // RNE
  return (unsigned short)(u >> 16);
}
__device__ inline unsigned pk2bf(float lo, float hi){
  float2 t; t.x = lo; t.y = hi;
  __hip_bfloat162 h = __float22bfloat162_rn(t);
  return *(unsigned*)&h;
}

// async global->LDS, 16B per lane
__device__ __forceinline__ void ld_g2l_16(const unsigned short* g, unsigned short* l){
  __builtin_amdgcn_global_load_lds(
      (const __attribute__((address_space(1))) void*)g,
      (__attribute__((address_space(3))) void*)l, 16, 0, 0);
}

// ---------------- kernel 1: fused X->bf16 + W->WT bf16 (one launch) ----------------
__global__ void convert_all(const float* __restrict__ hs, unsigned short* __restrict__ xb,
                            const float* __restrict__ wq, const float* __restrict__ wk,
                            const float* __restrict__ wv, unsigned short* __restrict__ wt){
  __shared__ unsigned short t[64][65];
  const int tid = threadIdx.x;
  if (blockIdx.x < 8192){
    const int i = blockIdx.x*256 + tid;
    float4 v = ((const float4*)hs)[i];
    ushort4 o;
    o.x = f2bf(v.x); o.y = f2bf(v.y); o.z = f2bf(v.z); o.w = f2bf(v.w);
    ((ushort4*)xb)[i] = o;
    return;
  }
  const int wtb = blockIdx.x - 8192;
  const int z   = wtb >> 8;              // 256 tiles per z
  const int rem = wtb & 255;
  const int kb  = (rem & 15)*64, nb = (rem >> 4)*64;
  const float* W = (z==0) ? wq : ((z==1) ? wk : wv);
  unsigned short* WT = wt + z*HH*HH;
  #pragma unroll
  for (int i = 0; i < 16; i++){
    const int idx = i*256 + tid;
    const int r = idx >> 6, c = idx & 63;
    t[r][c] = f2bf(W[(kb + r)*HH + nb + c]);
  }
  __syncthreads();
  #pragma unroll
  for (int i = 0; i < 16; i++){
    const int idx = i*256 + tid;
    const int n = idx >> 6, k = idx & 63;
    WT[(nb + n)*HH + kb + k] = t[k][n];
  }
}

// ---------------- kernel 2: QKV projection GEMM ----------------
// (R8/R9 version: 256x128 tile, 4 waves, 128x64/wave, 3-buffer counted-vmcnt(6),
//  pre-swizzled source + quad^swz reads, conflicts 0. Unchanged this round.)
__global__ __launch_bounds__(256) void qkv_gemm(
    const unsigned short* __restrict__ ws16, unsigned short* __restrict__ wsq,
    const float* __restrict__ bq, const float* __restrict__ bk, const float* __restrict__ bv,
    const float* __restrict__ qe, const float* __restrict__ ke, const float* __restrict__ ve,
    const int* __restrict__ idxp){
  __shared__ unsigned short al[3*256*32];   // 3 x 16KB  (A: 256 rows x 32 k)
  __shared__ unsigned short bl[3*128*32];   // 3 x 8KB   (B: 128 rows x 32 k)

  const unsigned short* Xb = ws16 + XB_OFF;
  const int z = blockIdx.z;
  const unsigned short* Wt = ws16 + WT_OFF + z*HH*HH;
  const float* bias = (z==0) ? bq : ((z==1) ? bk : bv);
  const float* emb  = (z==0) ? qe : ((z==1) ? ke : ve);

  const int tid  = threadIdx.x;
  const int wv   = tid >> 6;
  const int ln   = tid & 63;
  const int quad = ln >> 4;
  const int l15  = ln & 15;
  const int m0 = blockIdx.x * 256;
  const int n0 = blockIdx.y * 128;
  const int wm = wv & 1, wn = wv >> 1;       // wave tile: rows wm*128, cols wn*64
  const int swz = (l15 >> 1) & 3;            // read-side 16B-col XOR (R5-verified)

  const int sk  = (((tid & 3) ^ ((tid >> 3) & 3))) * 8;
  const int r0  = tid >> 2;
  const unsigned short* gA0 = &Xb[(size_t)(m0 + r0      )*HH + sk];
  const unsigned short* gA1 = &Xb[(size_t)(m0 + r0 +  64)*HH + sk];
  const unsigned short* gA2 = &Xb[(size_t)(m0 + r0 + 128)*HH + sk];
  const unsigned short* gA3 = &Xb[(size_t)(m0 + r0 + 192)*HH + sk];
  const unsigned short* gB0 = &Wt[(size_t)(n0 + r0      )*HH + sk];
  const unsigned short* gB1 = &Wt[(size_t)(n0 + r0 +  64)*HH + sk];
  unsigned short* aD = &al[wv*512];          // + c*2048 + SB*8192
  unsigned short* bD = &bl[wv*512];          // + c*2048 + SB*4096

  f32x4 acc[8][4] = {};

  // prologue: stage k=0 -> buf0, k=1 -> buf1 (12 loads in flight)
  ld_g2l_16(gA0,      aD);        ld_g2l_16(gA1,      aD + 2048);
  ld_g2l_16(gA2,      aD + 4096); ld_g2l_16(gA3,      aD + 6144);
  ld_g2l_16(gB0,      bD);        ld_g2l_16(gB1,      bD + 2048);
  ld_g2l_16(gA0 + 32, aD + 8192);        ld_g2l_16(gA1 + 32, aD + 8192 + 2048);
  ld_g2l_16(gA2 + 32, aD + 8192 + 4096); ld_g2l_16(gA3 + 32, aD + 8192 + 6144);
  ld_g2l_16(gB0 + 32, bD + 4096);        ld_g2l_16(gB1 + 32, bD + 4096 + 2048);

#define K_ITER(K, CUR, SB, DO_STAGE, VM)                                      \
  {                                                                           \
    asm volatile("s_waitcnt vmcnt(" #VM ")" ::: "memory");                    \
    __builtin_amdgcn_s_barrier();                                             \
    if (DO_STAGE){                                                            \
      const int ko = ((K) + 2) * 32;                                          \
      ld_g2l_16(gA0 + ko, aD + (SB)*8192);                                    \
      ld_g2l_16(gA1 + ko, aD + (SB)*8192 + 2048);                             \
      ld_g2l_16(gA2 + ko, aD + (SB)*8192 + 4096);                             \
      ld_g2l_16(gA3 + ko, aD + (SB)*8192 + 6144);                             \
      ld_g2l_16(gB0 + ko, bD + (SB)*4096);                                    \
      ld_g2l_16(gB1 + ko, bD + (SB)*4096 + 2048);                             \
    }                                                                         \
    const unsigned short* alc = &al[(CUR)*8192];                              \
    const unsigned short* blc = &bl[(CUR)*4096];                              \
    bf16x8 af[8], bf[4];                                                      \
    _Pragma("unroll")                                                         \
    for (int i = 0; i < 8; i++)                                               \
      af[i] = *(const bf16x8*)&alc[(wm*128 + i*16 + l15)*32 + (quad ^ swz)*8];\
    _Pragma("unroll")                                                         \
    for (int i = 0; i < 4; i++)                                               \
      bf[i] = *(const bf16x8*)&blc[(wn*64 + i*16 + l15)*32 + (quad ^ swz)*8]; \
    if (z == 2){                                                              \
      _Pragma("unroll")                                                       \
      for (int mi = 0; mi < 8; mi++)                                          \
        _Pragma("unroll")                                                     \
        for (int ni = 0; ni < 4; ni++)                                        \
          acc[mi][ni] = __builtin_amdgcn_mfma_f32_16x16x32_bf16(af[mi], bf[ni], acc[mi][ni], 0, 0, 0); \
    } else {                                                                  \
      _Pragma("unroll")                                                       \
      for (int mi = 0; mi < 8; mi++)                                          \
        _Pragma("unroll")                                                     \
        for (int ni = 0; ni < 4; ni++)                                        \
          acc[mi][ni] = __builtin_amdgcn_mfma_f32_16x16x32_bf16(bf[ni], af[mi], acc[mi][ni], 0, 0, 0); \
    }                                                                         \
  }

  for (int k = 0; k < 30; k += 3){
    K_ITER(k,     0, 2, 1, 6)
    K_ITER(k + 1, 1, 0, 1, 6)
    K_ITER(k + 2, 2, 1, 1, 6)
  }
  K_ITER(30, 0, 0, 0, 6)   // no stage; wait stage(30)
  K_ITER(31, 1, 0, 0, 0)   // no stage; drain stage(31)
#undef K_ITER

  const int index = idxp[0];
  if (z == 2){
    // V^T: [bh][d][s], normal orientation: lane holds 4 consecutive s -> ushort4
    #pragma unroll
    for (int ni = 0; ni < 4; ni++){
      const int n = n0 + wn*64 + ni*16 + l15;
      const float biasv = bias[n] + emb[index*HH + n];
      const int h = n >> 6, d = n & 63;
      #pragma unroll
      for (int mi = 0; mi < 8; mi++){
        const int g  = m0 + wm*128 + mi*16 + quad*4;  // 4 consecutive s (4-aligned)
        const int b_ = g >> 11;
        const int s_ = g & (SS - 1);
        const int bh = b_*NHH + h;
        const f32x4 a = acc[mi][ni];
        ushort4 o;
        o.x = f2bf(a[0] + biasv); o.y = f2bf(a[1] + biasv);
        o.z = f2bf(a[2] + biasv); o.w = f2bf(a[3] + biasv);
        *(ushort4*)&wsq[VT_OFF + (size_t)(bh*HDD + d)*SS + s_] = o;
      }
    }
  } else {
    // Q/K: [bh][s][d], swapped: lane holds 4 consecutive d at fixed s -> ushort4
    const float oscale = (z==0) ? 0.18033688011112042f : 1.0f;  // 0.125*log2(e)
    const size_t obase = (z==0) ? (size_t)Q_OFF : (size_t)K_OFF;
    #pragma unroll
    for (int mi = 0; mi < 8; mi++){
      const int sg = m0 + wm*128 + mi*16 + l15;       // s-row (from B-operand col)
      const int b_ = sg >> 11;
      const int s_ = sg & (SS - 1);
      #pragma unroll
      for (int ni = 0; ni < 4; ni++){
        const int nb = n0 + wn*64 + ni*16 + quad*4;   // 4 consecutive n (4-aligned)
        const int h  = nb >> 6, d0 = nb & 63;         // no h-cross (d0 % 4 == 0)
        const int bh = b_*NHH + h;
        const float4 b4 = *(const float4*)&bias[nb];
        const float4 e4 = *(const float4*)&emb[index*HH + nb];
        const f32x4 a = acc[mi][ni];
        ushort4 o;
        o.x = f2bf((a[0] + b4.x + e4.x) * oscale);
        o.y = f2bf((a[1] + b4.y + e4.y) * oscale);
        o.z = f2bf((a[2] + b4.z + e4.z) * oscale);
        o.w = f2bf((a[3] + b4.w + e4.w) * oscale);
        *(ushort4*)&wsq[obase + (size_t)(bh*SS + s_)*HDD + d0] = o;
      }
    }
  }
}

// ---------------- kernel 3: flash attention, 32q/wave, 8-wave blocks ----------------
// R10: attn was still ~80% LDS-BW-bound (R9 analysis: ka+va = 8KB/chunk/wave are
// IDENTICAL for all waves — lane-only dependent — so 16q/wave pays 1KB LDS per MFMA).
// 32 q-rows/wave (qg=2) amortizes the same 8KB over 2x MFMAs -> LDS traffic halves
// (~41us floor). Block = 8 waves = 256 q; grid = 512 = exactly 2 blocks/CU, all
// resident, zero tail. Keeps: staging role-split, swizzled conflict-free K, T12
// in-register P (2 permlane sets), mask-LDS, XCD pinning. Math identical per row.
#define LOG2E_F 1.4426950408889634f
__global__ __launch_bounds__(512) void attn_mfma(
    const unsigned short* __restrict__ ws16,
    const float* __restrict__ mask, float* __restrict__ out){
  __shared__ __align__(16) unsigned short kb[2][32*64];   // [kt][d], swizzled, 2x4KB
  __shared__ __align__(16) unsigned short vb[2][64*32];   // [d][kt], linear,   2x4KB
  __shared__ __align__(16) float mlds[SS];                // mask row * log2e, 8KB

  const int tid  = threadIdx.x;
  const int wave = tid >> 6;
  const int lane = tid & 63;
  const int quad = lane >> 4;
  const int l15  = lane & 15;

  // XCD-aware swizzle (bijective: 512 % 8 == 0): each head's 8 blocks on one XCD.
  const int bid  = (blockIdx.x & 7)*64 + (blockIdx.x >> 3);
  const int qb   = bid & 7;                  // 8 q-blocks of 256 rows per bh
  const int bh   = bid >> 3;
  const int b    = bh >> 4, h = bh & 15;
  const int q0   = qb*256 + wave*32;         // this wave's first q row

  const unsigned short* Qg = ws16 + Q_OFF  + (size_t)bh*SS*HDD;
  const unsigned short* Kg = ws16 + K_OFF  + (size_t)bh*SS*HDD;
  const unsigned short* Vg = ws16 + VT_OFF + (size_t)bh*HDD*SS;
  const float* maskB = mask + b*SS;

  // stage mask row * log2e (512 threads x float4 = 8KB)
  {
    float4 m4 = ((const float4*)maskB)[tid];
    m4.x*=LOG2E_F; m4.y*=LOG2E_F; m4.z*=LOG2E_F; m4.w*=LOG2E_F;
    *(float4*)&mlds[tid*4] = m4;
  }

  // resident Q fragments: B-operand (n=q=qg*16+l15, k=d=h2*32+quad*8+j)
  bf16x8 aq[2][2];
  #pragma unroll
  for (int qg = 0; qg < 2; qg++)
    #pragma unroll
    for (int h2 = 0; h2 < 2; h2++)
      aq[qg][h2] = *(const bf16x8*)(Qg + (size_t)(q0 + qg*16 + l15)*HDD + h2*32 + quad*8);

  // staging role split: waves 0-3 stage K (32 x 128B), waves 4-7 stage V (64 x 64B).
  // K source col pre-XOR-swizzled so linear dest yields LDS[kt][col ^ ((kt&7)<<4)].
  const unsigned short* sSrc;
  unsigned short* sDst;
  int sAdv;
  if (tid < 256){
    const int kr = tid >> 3, kp = tid & 7;
    sSrc = Kg + (size_t)kr*HDD + ((((kp*16) ^ ((kr&7)<<4)))>>1);
    sDst = &kb[0][0] + tid*8;                // 16B per thread, linear
    sAdv = 32*HDD;
  } else {
    const int t = tid - 256;
    const int vr = t >> 2, vp = t & 3;
    sSrc = Vg + (size_t)vr*SS + vp*8;
    sDst = &vb[0][0] + t*8;
    sAdv = 32;
  }

  f32x4 O[4][2] = {};            // O^T: elem (d=dg*16+quad*4+r, q=qg*16+l15)
  float lacc[2] = {0.f, 0.f};

  // prologue: stage chunk 0 into buffer 0 (syncthreads drains vmcnt)
  ld_g2l_16(sSrc, sDst);
  const unsigned short* sp = sSrc + sAdv;
  __syncthreads();

  #pragma unroll 2
  for (int ch = 0; ch < 64; ++ch){
    const int cur = ch & 1;
    const int ktb = ch*32;
    if (ch < 63){                // issue next-chunk stage BEFORE compute (overlap)
      ld_g2l_16(sp, sDst + (cur^1)*2048);
      sp += sAdv;
    }
    const unsigned short* kcur = &kb[cur][0];
    const unsigned short* vcur = &vb[cur][0];

    // K fragments: A-operand (m=kt=fi*16+l15, k=d), swizzled read (conflict-free)
    bf16x8 ka[2][2];
    #pragma unroll
    for (int fi = 0; fi < 2; fi++)
      #pragma unroll
      for (int h2 = 0; h2 < 2; h2++){
        const int colb = (h2*64 + quad*16) ^ ((l15 & 7) << 4);
        ka[fi][h2] = *(const bf16x8*)&kcur[(fi*16 + l15)*64 + (colb>>1)];
      }

    // S^T = K·Q^T with C init = mask*log2e -> p = exp2(st) -> pk pairs per (fi,qg)
    unsigned A0[2], A1[2], B0[2], B1[2];     // [qg]
    #pragma unroll
    for (int fi = 0; fi < 2; fi++){
      const f32x4 mv = *(const f32x4*)&mlds[ktb + fi*16 + quad*4];
      #pragma unroll
      for (int qg = 0; qg < 2; qg++){
        f32x4 st = mv;
        st = __builtin_amdgcn_mfma_f32_16x16x32_bf16(ka[fi][0], aq[qg][0], st, 0,0,0);
        st = __builtin_amdgcn_mfma_f32_16x16x32_bf16(ka[fi][1], aq[qg][1], st, 0,0,0);
        f32x4 p;
        #pragma unroll
        for (int r = 0; r < 4; r++) p[r] = __builtin_amdgcn_exp2f(st[r]);
        lacc[qg] += (p[0] + p[1]) + (p[2] + p[3]);
        const unsigned lo = pk2bf(p[0], p[1]), hi = pk2bf(p[2], p[3]);
        if (fi == 0){ A0[qg] = lo; A1[qg] = hi; }
        else        { B0[qg] = lo; B1[qg] = hi; }
      }
    }

    // V^T fragments: A-operand (m=d=dg*16+l15, k=kt=quad*8+j), 64B rows
    bf16x8 va[4];
    #pragma unroll
    for (int dg = 0; dg < 4; dg++)
      va[dg] = *(const bf16x8*)&vcur[(dg*16 + l15)*32 + quad*8];

    // in-register P redistribution (T12, R9-verified) + PV, per qg
    #pragma unroll
    for (int qg = 0; qg < 2; qg++){
      uint32x2 x   = __builtin_amdgcn_permlane32_swap(A0[qg], B0[qg], 0, 0);
      uint32x2 y   = __builtin_amdgcn_permlane32_swap(A1[qg], B1[qg], 0, 0);
      uint32x2 w02 = __builtin_amdgcn_permlane16_swap(x[0], x[1], 0, 0); // w0, w2
      uint32x2 w13 = __builtin_amdgcn_permlane16_swap(y[0], y[1], 0, 0); // w1, w3
      union { unsigned u[4]; bf16x8 v; } bpu;
      bpu.u[0] = w02[0]; bpu.u[1] = w13[0]; bpu.u[2] = w02[1]; bpu.u[3] = w13[1];
      const bf16x8 bp = bpu.v;
      #pragma unroll
      for (int dg = 0; dg < 4; dg++)
        O[dg][qg] = __builtin_amdgcn_mfma_f32_16x16x32_bf16(va[dg], bp, O[dg][qg], 0,0,0);
    }

    __syncthreads();   // all waves done reading cur; next-chunk stage drained
  }

  // row sums + epilogue per qg
  #pragma unroll
  for (int qg = 0; qg < 2; qg++){
    float lq = lacc[qg];
    lq += __shfl_xor(lq, 16);
    lq += __shfl_xor(lq, 32);
    const float inv = 1.0f / lq;
    float* op = out + ((size_t)b*SS + q0 + qg*16 + l15)*HH + h*HDD + quad*4;
    #pragma unroll
    for (int dg = 0; dg < 4; dg++){
      f32x4 v = O[dg][qg];
      float4 o; o.x = v[0]*inv; o.y = v[1]*inv; o.z = v[2]*inv; o.w = v[3]*inv;
      *(float4*)(op + dg*16) = o;
    }
  }
}

extern "C" void kernel_launch(void* const* d_in, const int* in_sizes, int n_in,
                              void* d_out, int out_size, void* d_ws, size_t ws_size,
                              hipStream_t stream){
  const float* hs   = (const float*)d_in[0];
  const float* mask = (const float*)d_in[1];
  const float* Wq   = (const float*)d_in[2];
  const float* bq   = (const float*)d_in[3];
  const float* Wk   = (const float*)d_in[4];
  const float* bk   = (const float*)d_in[5];
  const float* Wv   = (const float*)d_in[6];
  const float* bv   = (const float*)d_in[7];
  const float* qe   = (const float*)d_in[8];
  const float* ke   = (const float*)d_in[9];
  const float* ve   = (const float*)d_in[10];
  const int*   idx  = (const int*)d_in[11];
  unsigned short* ws16 = (unsigned short*)d_ws;
  float* out = (float*)d_out;

  convert_all<<<8192 + 768, 256, 0, stream>>>(hs, ws16 + XB_OFF, Wq, Wk, Wv, ws16 + WT_OFF);

  dim3 g2(M_TOT/256, HH/128, 3);
  qkv_gemm<<<g2, 256, 0, stream>>>(ws16, ws16, bq, bk, bv, qe, ke, ve, idx);

  attn_mfma<<<BB*NHH*SS/256, 512, 0, stream>>>(ws16, mask, out);
}

// Round 11
// 269.765 us; speedup vs baseline: 1.1804x; 1.0441x over previous
//
#include <hip/hip_runtime.h>
#include <hip/hip_bf16.h>
#include <stdint.h>

#define BB 4
#define SS 2048
#define HH 1024
#define NHH 16
#define HDD 64
#define M_TOT (BB*SS)          // 8192

// workspace layout (ushort/bf16 element offsets)
#define XB_OFF 0                              // hidden bf16 [8192][1024]
#define WT_OFF (M_TOT*HH)                     // Wq^T,Wk^T,Wv^T bf16 [3][N=1024][K=1024]
#define Q_OFF  (WT_OFF + 3*HH*HH)             // Q  [B][NH][S][HD]  (pre-scaled by 0.125*log2e!)
#define K_OFF  (Q_OFF + BB*NHH*SS*HDD)        // K  [B][NH][S][HD]
#define VT_OFF (K_OFF + BB*NHH*SS*HDD)        // Vt [B][NH][HD][S]  (transposed)

typedef short bf16x8 __attribute__((ext_vector_type(8)));
typedef float f32x4  __attribute__((ext_vector_type(4)));
typedef unsigned uint32x2 __attribute__((ext_vector_type(2)));

__device__ inline unsigned short f2bf(float f){
  unsigned u = __float_as_uint(f);
  u += 0x7fffu + ((u >> 16) & 1u);   // RNE
  return (unsigned short)(u >> 16);
}
__device__ inline unsigned pk2bf(float lo, float hi){
  float2 t; t.x = lo; t.y = hi;
  __hip_bfloat162 h = __float22bfloat162_rn(t);
  return *(unsigned*)&h;
}

// async global->LDS, 16B per lane
__device__ __forceinline__ void ld_g2l_16(const unsigned short* g, unsigned short* l){
  __builtin_amdgcn_global_load_lds(
      (const __attribute__((address_space(1))) void*)g,
      (__attribute__((address_space(3))) void*)l, 16, 0, 0);
}

// ---------------- kernel 1: fused X->bf16 + W->WT bf16 (one launch) ----------------
__global__ void convert_all(const float* __restrict__ hs, unsigned short* __restrict__ xb,
                            const float* __restrict__ wq, const float* __restrict__ wk,
                            const float* __restrict__ wv, unsigned short* __restrict__ wt){
  __shared__ unsigned short t[64][65];
  const int tid = threadIdx.x;
  if (blockIdx.x < 8192){
    const int i = blockIdx.x*256 + tid;
    float4 v = ((const float4*)hs)[i];
    ushort4 o;
    o.x = f2bf(v.x); o.y = f2bf(v.y); o.z = f2bf(v.z); o.w = f2bf(v.w);
    ((ushort4*)xb)[i] = o;
    return;
  }
  const int wtb = blockIdx.x - 8192;
  const int z   = wtb >> 8;              // 256 tiles per z
  const int rem = wtb & 255;
  const int kb  = (rem & 15)*64, nb = (rem >> 4)*64;
  const float* W = (z==0) ? wq : ((z==1) ? wk : wv);
  unsigned short* WT = wt + z*HH*HH;
  #pragma unroll
  for (int i = 0; i < 16; i++){
    const int idx = i*256 + tid;
    const int r = idx >> 6, c = idx & 63;
    t[r][c] = f2bf(W[(kb + r)*HH + nb + c]);
  }
  __syncthreads();
  #pragma unroll
  for (int i = 0; i < 16; i++){
    const int idx = i*256 + tid;
    const int n = idx >> 6, k = idx & 63;
    WT[(nb + n)*HH + kb + k] = t[k][n];
  }
}

// ---------------- kernel 2: QKV projection GEMM ----------------
// R11: 8-wave occupancy restructure. R10 diagnosis: occupancy pinned ~11% across all
// 4-wave configs; VGPR 244 + 128 AGPR (acc[8][4]) > 256 unified-RF budget -> 1
// wave/SIMD, pure latency exposure (2600 cy/iter vs 250 cy work). attn's 512-thread
// blocks measure 63% occupancy on this chip -> qkv goes 512-thread / 8-wave:
//   tile 256x128, per-wave 64x64 (acc[4][4] = 64 AGPR, total regs ~200 <= 256
//   -> 2 waves/SIMD; LDS 72KB -> 2 blocks/CU -> 16 waves/CU theoretical).
// Schedule: R5's verified 3-buffer / depth-2 / counted-vmcnt, now 3 loads/thread/iter
// (A 2 + B 1) -> vmcnt(3); raw s_barrier; pre-swizzled source + quad^swz reads
// (conflicts measured 0 at this exact read pattern, R5/R8).
// z in {0,1}: swapped MFMA -> lane holds 4 consecutive d -> ushort4 stores.
// z==2 (V^T): normal MFMA -> lane holds 4 consecutive s -> ushort4 stores.
__global__ __launch_bounds__(512) void qkv_gemm(
    const unsigned short* __restrict__ ws16, unsigned short* __restrict__ wsq,
    const float* __restrict__ bq, const float* __restrict__ bk, const float* __restrict__ bv,
    const float* __restrict__ qe, const float* __restrict__ ke, const float* __restrict__ ve,
    const int* __restrict__ idxp){
  __shared__ unsigned short al[3*256*32];   // 3 x 16KB  (A: 256 rows x 32 k)
  __shared__ unsigned short bl[3*128*32];   // 3 x 8KB   (B: 128 rows x 32 k)

  const unsigned short* Xb = ws16 + XB_OFF;
  const int z = blockIdx.z;
  const unsigned short* Wt = ws16 + WT_OFF + z*HH*HH;
  const float* bias = (z==0) ? bq : ((z==1) ? bk : bv);
  const float* emb  = (z==0) ? qe : ((z==1) ? ke : ve);

  const int tid  = threadIdx.x;
  const int wv   = tid >> 6;
  const int ln   = tid & 63;
  const int quad = ln >> 4;
  const int l15  = ln & 15;
  const int m0 = blockIdx.x * 256;
  const int n0 = blockIdx.y * 128;
  const int wm = wv & 3, wn = wv >> 2;       // wave tile: rows wm*64, cols wn*64
  const int swz = (l15 >> 1) & 3;            // read-side 16B-col XOR (R5-verified)

  // staging: thread t stages A pieces {t, t+512} (rows t>>2, t>>2+128) and B piece t
  // (row t>>2). 16B piece (t&3), source col pre-XOR-swizzled by ((row>>1)&3) ==
  // ((t>>3)&3) for all three (row offsets 128/0 are 0 mod 4 after >>1).
  const int sk = (((tid & 3) ^ ((tid >> 3) & 3))) * 8;
  const int r0 = tid >> 2;                   // 0..127
  const unsigned short* gA0 = &Xb[(size_t)(m0 + r0      )*HH + sk];
  const unsigned short* gA1 = &Xb[(size_t)(m0 + r0 + 128)*HH + sk];
  const unsigned short* gB0 = &Wt[(size_t)(n0 + r0      )*HH + sk];
  unsigned short* aD = &al[wv*512];          // wave-linear dest (+lane*16B by HW)
  unsigned short* bD = &bl[wv*512];

  f32x4 acc[4][4] = {};

  // prologue: stage k=0 -> buf0, k=1 -> buf1 (6 loads in flight)
  ld_g2l_16(gA0,      aD);        ld_g2l_16(gA1,      aD + 4096);
  ld_g2l_16(gB0,      bD);
  ld_g2l_16(gA0 + 32, aD + 8192); ld_g2l_16(gA1 + 32, aD + 8192 + 4096);
  ld_g2l_16(gB0 + 32, bD + 4096);

#define K_ITER(K, CUR, SB, DO_STAGE, VM)                                      \
  {                                                                           \
    asm volatile("s_waitcnt vmcnt(" #VM ")" ::: "memory");                    \
    __builtin_amdgcn_s_barrier();                                             \
    if (DO_STAGE){                                                            \
      const int ko = ((K) + 2) * 32;                                          \
      ld_g2l_16(gA0 + ko, aD + (SB)*8192);                                    \
      ld_g2l_16(gA1 + ko, aD + (SB)*8192 + 4096);                             \
      ld_g2l_16(gB0 + ko, bD + (SB)*4096);                                    \
    }                                                                         \
    const unsigned short* alc = &al[(CUR)*8192];                              \
    const unsigned short* blc = &bl[(CUR)*4096];                              \
    bf16x8 af[4], bf[4];                                                      \
    _Pragma("unroll")                                                         \
    for (int i = 0; i < 4; i++){                                              \
      af[i] = *(const bf16x8*)&alc[(wm*64 + i*16 + l15)*32 + (quad ^ swz)*8]; \
      bf[i] = *(const bf16x8*)&blc[(wn*64 + i*16 + l15)*32 + (quad ^ swz)*8]; \
    }                                                                         \
    if (z == 2){                                                              \
      _Pragma("unroll")                                                       \
      for (int mi = 0; mi < 4; mi++)                                          \
        _Pragma("unroll")                                                     \
        for (int ni = 0; ni < 4; ni++)                                        \
          acc[mi][ni] = __builtin_amdgcn_mfma_f32_16x16x32_bf16(af[mi], bf[ni], acc[mi][ni], 0, 0, 0); \
    } else {                                                                  \
      _Pragma("unroll")                                                       \
      for (int mi = 0; mi < 4; mi++)                                          \
        _Pragma("unroll")                                                     \
        for (int ni = 0; ni < 4; ni++)                                        \
          acc[mi][ni] = __builtin_amdgcn_mfma_f32_16x16x32_bf16(bf[ni], af[mi], acc[mi][ni], 0, 0, 0); \
    }                                                                         \
  }

  for (int k = 0; k < 30; k += 3){
    K_ITER(k,     0, 2, 1, 3)
    K_ITER(k + 1, 1, 0, 1, 3)
    K_ITER(k + 2, 2, 1, 1, 3)
  }
  K_ITER(30, 0, 0, 0, 3)   // no stage; wait stage(30)
  K_ITER(31, 1, 0, 0, 0)   // no stage; drain stage(31)
#undef K_ITER

  const int index = idxp[0];
  if (z == 2){
    // V^T: [bh][d][s], normal orientation: lane holds 4 consecutive s -> ushort4
    #pragma unroll
    for (int ni = 0; ni < 4; ni++){
      const int n = n0 + wn*64 + ni*16 + l15;
      const float biasv = bias[n] + emb[index*HH + n];
      const int h = n >> 6, d = n & 63;
      #pragma unroll
      for (int mi = 0; mi < 4; mi++){
        const int g  = m0 + wm*64 + mi*16 + quad*4;   // 4 consecutive s (4-aligned)
        const int b_ = g >> 11;
        const int s_ = g & (SS - 1);
        const int bh = b_*NHH + h;
        const f32x4 a = acc[mi][ni];
        ushort4 o;
        o.x = f2bf(a[0] + biasv); o.y = f2bf(a[1] + biasv);
        o.z = f2bf(a[2] + biasv); o.w = f2bf(a[3] + biasv);
        *(ushort4*)&wsq[VT_OFF + (size_t)(bh*HDD + d)*SS + s_] = o;
      }
    }
  } else {
    // Q/K: [bh][s][d], swapped: lane holds 4 consecutive d at fixed s -> ushort4
    const float oscale = (z==0) ? 0.18033688011112042f : 1.0f;  // 0.125*log2(e)
    const size_t obase = (z==0) ? (size_t)Q_OFF : (size_t)K_OFF;
    #pragma unroll
    for (int mi = 0; mi < 4; mi++){
      const int sg = m0 + wm*64 + mi*16 + l15;        // s-row (from B-operand col)
      const int b_ = sg >> 11;
      const int s_ = sg & (SS - 1);
      #pragma unroll
      for (int ni = 0; ni < 4; ni++){
        const int nb = n0 + wn*64 + ni*16 + quad*4;   // 4 consecutive n (4-aligned)
        const int h  = nb >> 6, d0 = nb & 63;         // no h-cross (d0 % 4 == 0)
        const int bh = b_*NHH + h;
        const float4 b4 = *(const float4*)&bias[nb];
        const float4 e4 = *(const float4*)&emb[index*HH + nb];
        const f32x4 a = acc[mi][ni];
        ushort4 o;
        o.x = f2bf((a[0] + b4.x + e4.x) * oscale);
        o.y = f2bf((a[1] + b4.y + e4.y) * oscale);
        o.z = f2bf((a[2] + b4.z + e4.z) * oscale);
        o.w = f2bf((a[3] + b4.w + e4.w) * oscale);
        *(ushort4*)&wsq[obase + (size_t)(bh*SS + s_)*HDD + d0] = o;
      }
    }
  }
}

// ---------------- kernel 3: flash attention, 32q/wave, 8-wave blocks ----------------
// (R10 version — unchanged this round.)
#define LOG2E_F 1.4426950408889634f
__global__ __launch_bounds__(512) void attn_mfma(
    const unsigned short* __restrict__ ws16,
    const float* __restrict__ mask, float* __restrict__ out){
  __shared__ __align__(16) unsigned short kb[2][32*64];   // [kt][d], swizzled, 2x4KB
  __shared__ __align__(16) unsigned short vb[2][64*32];   // [d][kt], linear,   2x4KB
  __shared__ __align__(16) float mlds[SS];                // mask row * log2e, 8KB

  const int tid  = threadIdx.x;
  const int wave = tid >> 6;
  const int lane = tid & 63;
  const int quad = lane >> 4;
  const int l15  = lane & 15;

  // XCD-aware swizzle (bijective: 512 % 8 == 0): each head's 8 blocks on one XCD.
  const int bid  = (blockIdx.x & 7)*64 + (blockIdx.x >> 3);
  const int qb   = bid & 7;                  // 8 q-blocks of 256 rows per bh
  const int bh   = bid >> 3;
  const int b    = bh >> 4, h = bh & 15;
  const int q0   = qb*256 + wave*32;         // this wave's first q row

  const unsigned short* Qg = ws16 + Q_OFF  + (size_t)bh*SS*HDD;
  const unsigned short* Kg = ws16 + K_OFF  + (size_t)bh*SS*HDD;
  const unsigned short* Vg = ws16 + VT_OFF + (size_t)bh*HDD*SS;
  const float* maskB = mask + b*SS;

  // stage mask row * log2e (512 threads x float4 = 8KB)
  {
    float4 m4 = ((const float4*)maskB)[tid];
    m4.x*=LOG2E_F; m4.y*=LOG2E_F; m4.z*=LOG2E_F; m4.w*=LOG2E_F;
    *(float4*)&mlds[tid*4] = m4;
  }

  // resident Q fragments: B-operand (n=q=qg*16+l15, k=d=h2*32+quad*8+j)
  bf16x8 aq[2][2];
  #pragma unroll
  for (int qg = 0; qg < 2; qg++)
    #pragma unroll
    for (int h2 = 0; h2 < 2; h2++)
      aq[qg][h2] = *(const bf16x8*)(Qg + (size_t)(q0 + qg*16 + l15)*HDD + h2*32 + quad*8);

  // staging role split: waves 0-3 stage K (32 x 128B), waves 4-7 stage V (64 x 64B).
  // K source col pre-XOR-swizzled so linear dest yields LDS[kt][col ^ ((kt&7)<<4)].
  const unsigned short* sSrc;
  unsigned short* sDst;
  int sAdv;
  if (tid < 256){
    const int kr = tid >> 3, kp = tid & 7;
    sSrc = Kg + (size_t)kr*HDD + ((((kp*16) ^ ((kr&7)<<4)))>>1);
    sDst = &kb[0][0] + tid*8;                // 16B per thread, linear
    sAdv = 32*HDD;
  } else {
    const int t = tid - 256;
    const int vr = t >> 2, vp = t & 3;
    sSrc = Vg + (size_t)vr*SS + vp*8;
    sDst = &vb[0][0] + t*8;
    sAdv = 32;
  }

  f32x4 O[4][2] = {};            // O^T: elem (d=dg*16+quad*4+r, q=qg*16+l15)
  float lacc[2] = {0.f, 0.f};

  // prologue: stage chunk 0 into buffer 0 (syncthreads drains vmcnt)
  ld_g2l_16(sSrc, sDst);
  const unsigned short* sp = sSrc + sAdv;
  __syncthreads();

  #pragma unroll 2
  for (int ch = 0; ch < 64; ++ch){
    const int cur = ch & 1;
    const int ktb = ch*32;
    if (ch < 63){                // issue next-chunk stage BEFORE compute (overlap)
      ld_g2l_16(sp, sDst + (cur^1)*2048);
      sp += sAdv;
    }
    const unsigned short* kcur = &kb[cur][0];
    const unsigned short* vcur = &vb[cur][0];

    // K fragments: A-operand (m=kt=fi*16+l15, k=d), swizzled read (conflict-free)
    bf16x8 ka[2][2];
    #pragma unroll
    for (int fi = 0; fi < 2; fi++)
      #pragma unroll
      for (int h2 = 0; h2 < 2; h2++){
        const int colb = (h2*64 + quad*16) ^ ((l15 & 7) << 4);
        ka[fi][h2] = *(const bf16x8*)&kcur[(fi*16 + l15)*64 + (colb>>1)];
      }

    // S^T = K·Q^T with C init = mask*log2e -> p = exp2(st) -> pk pairs per (fi,qg)
    unsigned A0[2], A1[2], B0[2], B1[2];     // [qg]
    #pragma unroll
    for (int fi = 0; fi < 2; fi++){
      const f32x4 mv = *(const f32x4*)&mlds[ktb + fi*16 + quad*4];
      #pragma unroll
      for (int qg = 0; qg < 2; qg++){
        f32x4 st = mv;
        st = __builtin_amdgcn_mfma_f32_16x16x32_bf16(ka[fi][0], aq[qg][0], st, 0,0,0);
        st = __builtin_amdgcn_mfma_f32_16x16x32_bf16(ka[fi][1], aq[qg][1], st, 0,0,0);
        f32x4 p;
        #pragma unroll
        for (int r = 0; r < 4; r++) p[r] = __builtin_amdgcn_exp2f(st[r]);
        lacc[qg] += (p[0] + p[1]) + (p[2] + p[3]);
        const unsigned lo = pk2bf(p[0], p[1]), hi = pk2bf(p[2], p[3]);
        if (fi == 0){ A0[qg] = lo; A1[qg] = hi; }
        else        { B0[qg] = lo; B1[qg] = hi; }
      }
    }

    // V^T fragments: A-operand (m=d=dg*16+l15, k=kt=quad*8+j), 64B rows
    bf16x8 va[4];
    #pragma unroll
    for (int dg = 0; dg < 4; dg++)
      va[dg] = *(const bf16x8*)&vcur[(dg*16 + l15)*32 + quad*8];

    // in-register P redistribution (T12, R9-verified) + PV, per qg
    #pragma unroll
    for (int qg = 0; qg < 2; qg++){
      uint32x2 x   = __builtin_amdgcn_permlane32_swap(A0[qg], B0[qg], 0, 0);
      uint32x2 y   = __builtin_amdgcn_permlane32_swap(A1[qg], B1[qg], 0, 0);
      uint32x2 w02 = __builtin_amdgcn_permlane16_swap(x[0], x[1], 0, 0); // w0, w2
      uint32x2 w13 = __builtin_amdgcn_permlane16_swap(y[0], y[1], 0, 0); // w1, w3
      union { unsigned u[4]; bf16x8 v; } bpu;
      bpu.u[0] = w02[0]; bpu.u[1] = w13[0]; bpu.u[2] = w02[1]; bpu.u[3] = w13[1];
      const bf16x8 bp = bpu.v;
      #pragma unroll
      for (int dg = 0; dg < 4; dg++)
        O[dg][qg] = __builtin_amdgcn_mfma_f32_16x16x32_bf16(va[dg], bp, O[dg][qg], 0,0,0);
    }

    __syncthreads();   // all waves done reading cur; next-chunk stage drained
  }

  // row sums + epilogue per qg
  #pragma unroll
  for (int qg = 0; qg < 2; qg++){
    float lq = lacc[qg];
    lq += __shfl_xor(lq, 16);
    lq += __shfl_xor(lq, 32);
    const float inv = 1.0f / lq;
    float* op = out + ((size_t)b*SS + q0 + qg*16 + l15)*HH + h*HDD + quad*4;
    #pragma unroll
    for (int dg = 0; dg < 4; dg++){
      f32x4 v = O[dg][qg];
      float4 o; o.x = v[0]*inv; o.y = v[1]*inv; o.z = v[2]*inv; o.w = v[3]*inv;
      *(float4*)(op + dg*16) = o;
    }
  }
}

extern "C" void kernel_launch(void* const* d_in, const int* in_sizes, int n_in,
                              void* d_out, int out_size, void* d_ws, size_t ws_size,
                              hipStream_t stream){
  const float* hs   = (const float*)d_in[0];
  const float* mask = (const float*)d_in[1];
  const float* Wq   = (const float*)d_in[2];
  const float* bq   = (const float*)d_in[3];
  const float* Wk   = (const float*)d_in[4];
  const float* bk   = (const float*)d_in[5];
  const float* Wv   = (const float*)d_in[6];
  const float* bv   = (const float*)d_in[7];
  const float* qe   = (const float*)d_in[8];
  const float* ke   = (const float*)d_in[9];
  const float* ve   = (const float*)d_in[10];
  const int*   idx  = (const int*)d_in[11];
  unsigned short* ws16 = (unsigned short*)d_ws;
  float* out = (float*)d_out;

  convert_all<<<8192 + 768, 256, 0, stream>>>(hs, ws16 + XB_OFF, Wq, Wk, Wv, ws16 + WT_OFF);

  dim3 g2(M_TOT/256, HH/128, 3);
  qkv_gemm<<<g2, 512, 0, stream>>>(ws16, ws16, bq, bk, bv, qe, ke, ve, idx);

  attn_mfma<<<BB*NHH*SS/256, 512, 0, stream>>>(ws16, mask, out);
}

// Round 12
// 264.172 us; speedup vs baseline: 1.2054x; 1.0212x over previous
//
#include <hip/hip_runtime.h>
#include <hip/hip_bf16.h>
#include <stdint.h>

#define BB 4
#define SS 2048
#define HH 1024
#define NHH 16
#define HDD 64
#define M_TOT (BB*SS)          // 8192

// workspace layout (ushort/bf16 element offsets)
#define XB_OFF 0                              // hidden bf16 [8192][1024]
#define WT_OFF (M_TOT*HH)                     // Wq^T,Wk^T,Wv^T bf16 [3][N=1024][K=1024]
#define Q_OFF  (WT_OFF + 3*HH*HH)             // Q  [B][NH][S][HD]  (pre-scaled by 0.125*log2e!)
#define K_OFF  (Q_OFF + BB*NHH*SS*HDD)        // K  [B][NH][S][HD]
#define VT_OFF (K_OFF + BB*NHH*SS*HDD)        // Vt [B][NH][HD][S]  (transposed)

typedef short bf16x8 __attribute__((ext_vector_type(8)));
typedef float f32x4  __attribute__((ext_vector_type(4)));
typedef unsigned uint32x2 __attribute__((ext_vector_type(2)));

__device__ inline unsigned short f2bf(float f){
  unsigned u = __float_as_uint(f);
  u += 0x7fffu + ((u >> 16) & 1u);   // RNE
  return (unsigned short)(u >> 16);
}
__device__ inline unsigned pk2bf(float lo, float hi){
  float2 t; t.x = lo; t.y = hi;
  __hip_bfloat162 h = __float22bfloat162_rn(t);
  return *(unsigned*)&h;
}

// async global->LDS, 16B per lane
__device__ __forceinline__ void ld_g2l_16(const unsigned short* g, unsigned short* l){
  __builtin_amdgcn_global_load_lds(
      (const __attribute__((address_space(1))) void*)g,
      (__attribute__((address_space(3))) void*)l, 16, 0, 0);
}

// ---------------- kernel 1: fused X->bf16 + W->WT bf16 (one launch) ----------------
__global__ void convert_all(const float* __restrict__ hs, unsigned short* __restrict__ xb,
                            const float* __restrict__ wq, const float* __restrict__ wk,
                            const float* __restrict__ wv, unsigned short* __restrict__ wt){
  __shared__ unsigned short t[64][65];
  const int tid = threadIdx.x;
  if (blockIdx.x < 8192){
    const int i = blockIdx.x*256 + tid;
    float4 v = ((const float4*)hs)[i];
    ushort4 o;
    o.x = f2bf(v.x); o.y = f2bf(v.y); o.z = f2bf(v.z); o.w = f2bf(v.w);
    ((ushort4*)xb)[i] = o;
    return;
  }
  const int wtb = blockIdx.x - 8192;
  const int z   = wtb >> 8;              // 256 tiles per z
  const int rem = wtb & 255;
  const int kb  = (rem & 15)*64, nb = (rem >> 4)*64;
  const float* W = (z==0) ? wq : ((z==1) ? wk : wv);
  unsigned short* WT = wt + z*HH*HH;
  #pragma unroll
  for (int i = 0; i < 16; i++){
    const int idx = i*256 + tid;
    const int r = idx >> 6, c = idx & 63;
    t[r][c] = f2bf(W[(kb + r)*HH + nb + c]);
  }
  __syncthreads();
  #pragma unroll
  for (int i = 0; i < 16; i++){
    const int idx = i*256 + tid;
    const int n = idx >> 6, k = idx & 63;
    WT[(nb + n)*HH + kb + k] = t[k][n];
  }
}

// ---------------- kernel 2: QKV projection GEMM ----------------
// (R11 version: 512-thread / 8-wave, 256x128 tile, 64x64/wave, 3-buffer counted
//  vmcnt(3); fell out of top-5 at <91us. Unchanged this round.)
__global__ __launch_bounds__(512) void qkv_gemm(
    const unsigned short* __restrict__ ws16, unsigned short* __restrict__ wsq,
    const float* __restrict__ bq, const float* __restrict__ bk, const float* __restrict__ bv,
    const float* __restrict__ qe, const float* __restrict__ ke, const float* __restrict__ ve,
    const int* __restrict__ idxp){
  __shared__ unsigned short al[3*256*32];   // 3 x 16KB  (A: 256 rows x 32 k)
  __shared__ unsigned short bl[3*128*32];   // 3 x 8KB   (B: 128 rows x 32 k)

  const unsigned short* Xb = ws16 + XB_OFF;
  const int z = blockIdx.z;
  const unsigned short* Wt = ws16 + WT_OFF + z*HH*HH;
  const float* bias = (z==0) ? bq : ((z==1) ? bk : bv);
  const float* emb  = (z==0) ? qe : ((z==1) ? ke : ve);

  const int tid  = threadIdx.x;
  const int wv   = tid >> 6;
  const int ln   = tid & 63;
  const int quad = ln >> 4;
  const int l15  = ln & 15;
  const int m0 = blockIdx.x * 256;
  const int n0 = blockIdx.y * 128;
  const int wm = wv & 3, wn = wv >> 2;       // wave tile: rows wm*64, cols wn*64
  const int swz = (l15 >> 1) & 3;            // read-side 16B-col XOR (R5-verified)

  const int sk = (((tid & 3) ^ ((tid >> 3) & 3))) * 8;
  const int r0 = tid >> 2;                   // 0..127
  const unsigned short* gA0 = &Xb[(size_t)(m0 + r0      )*HH + sk];
  const unsigned short* gA1 = &Xb[(size_t)(m0 + r0 + 128)*HH + sk];
  const unsigned short* gB0 = &Wt[(size_t)(n0 + r0      )*HH + sk];
  unsigned short* aD = &al[wv*512];          // wave-linear dest (+lane*16B by HW)
  unsigned short* bD = &bl[wv*512];

  f32x4 acc[4][4] = {};

  // prologue: stage k=0 -> buf0, k=1 -> buf1 (6 loads in flight)
  ld_g2l_16(gA0,      aD);        ld_g2l_16(gA1,      aD + 4096);
  ld_g2l_16(gB0,      bD);
  ld_g2l_16(gA0 + 32, aD + 8192); ld_g2l_16(gA1 + 32, aD + 8192 + 4096);
  ld_g2l_16(gB0 + 32, bD + 4096);

#define K_ITER(K, CUR, SB, DO_STAGE, VM)                                      \
  {                                                                           \
    asm volatile("s_waitcnt vmcnt(" #VM ")" ::: "memory");                    \
    __builtin_amdgcn_s_barrier();                                             \
    if (DO_STAGE){                                                            \
      const int ko = ((K) + 2) * 32;                                          \
      ld_g2l_16(gA0 + ko, aD + (SB)*8192);                                    \
      ld_g2l_16(gA1 + ko, aD + (SB)*8192 + 4096);                             \
      ld_g2l_16(gB0 + ko, bD + (SB)*4096);                                    \
    }                                                                         \
    const unsigned short* alc = &al[(CUR)*8192];                              \
    const unsigned short* blc = &bl[(CUR)*4096];                              \
    bf16x8 af[4], bf[4];                                                      \
    _Pragma("unroll")                                                         \
    for (int i = 0; i < 4; i++){                                              \
      af[i] = *(const bf16x8*)&alc[(wm*64 + i*16 + l15)*32 + (quad ^ swz)*8]; \
      bf[i] = *(const bf16x8*)&blc[(wn*64 + i*16 + l15)*32 + (quad ^ swz)*8]; \
    }                                                                         \
    if (z == 2){                                                              \
      _Pragma("unroll")                                                       \
      for (int mi = 0; mi < 4; mi++)                                          \
        _Pragma("unroll")                                                     \
        for (int ni = 0; ni < 4; ni++)                                        \
          acc[mi][ni] = __builtin_amdgcn_mfma_f32_16x16x32_bf16(af[mi], bf[ni], acc[mi][ni], 0, 0, 0); \
    } else {                                                                  \
      _Pragma("unroll")                                                       \
      for (int mi = 0; mi < 4; mi++)                                          \
        _Pragma("unroll")                                                     \
        for (int ni = 0; ni < 4; ni++)                                        \
          acc[mi][ni] = __builtin_amdgcn_mfma_f32_16x16x32_bf16(bf[ni], af[mi], acc[mi][ni], 0, 0, 0); \
    }                                                                         \
  }

  for (int k = 0; k < 30; k += 3){
    K_ITER(k,     0, 2, 1, 3)
    K_ITER(k + 1, 1, 0, 1, 3)
    K_ITER(k + 2, 2, 1, 1, 3)
  }
  K_ITER(30, 0, 0, 0, 3)   // no stage; wait stage(30)
  K_ITER(31, 1, 0, 0, 0)   // no stage; drain stage(31)
#undef K_ITER

  const int index = idxp[0];
  if (z == 2){
    // V^T: [bh][d][s], normal orientation: lane holds 4 consecutive s -> ushort4
    #pragma unroll
    for (int ni = 0; ni < 4; ni++){
      const int n = n0 + wn*64 + ni*16 + l15;
      const float biasv = bias[n] + emb[index*HH + n];
      const int h = n >> 6, d = n & 63;
      #pragma unroll
      for (int mi = 0; mi < 4; mi++){
        const int g  = m0 + wm*64 + mi*16 + quad*4;   // 4 consecutive s (4-aligned)
        const int b_ = g >> 11;
        const int s_ = g & (SS - 1);
        const int bh = b_*NHH + h;
        const f32x4 a = acc[mi][ni];
        ushort4 o;
        o.x = f2bf(a[0] + biasv); o.y = f2bf(a[1] + biasv);
        o.z = f2bf(a[2] + biasv); o.w = f2bf(a[3] + biasv);
        *(ushort4*)&wsq[VT_OFF + (size_t)(bh*HDD + d)*SS + s_] = o;
      }
    }
  } else {
    // Q/K: [bh][s][d], swapped: lane holds 4 consecutive d at fixed s -> ushort4
    const float oscale = (z==0) ? 0.18033688011112042f : 1.0f;  // 0.125*log2(e)
    const size_t obase = (z==0) ? (size_t)Q_OFF : (size_t)K_OFF;
    #pragma unroll
    for (int mi = 0; mi < 4; mi++){
      const int sg = m0 + wm*64 + mi*16 + l15;        // s-row (from B-operand col)
      const int b_ = sg >> 11;
      const int s_ = sg & (SS - 1);
      #pragma unroll
      for (int ni = 0; ni < 4; ni++){
        const int nb = n0 + wn*64 + ni*16 + quad*4;   // 4 consecutive n (4-aligned)
        const int h  = nb >> 6, d0 = nb & 63;         // no h-cross (d0 % 4 == 0)
        const int bh = b_*NHH + h;
        const float4 b4 = *(const float4*)&bias[nb];
        const float4 e4 = *(const float4*)&emb[index*HH + nb];
        const f32x4 a = acc[mi][ni];
        ushort4 o;
        o.x = f2bf((a[0] + b4.x + e4.x) * oscale);
        o.y = f2bf((a[1] + b4.y + e4.y) * oscale);
        o.z = f2bf((a[2] + b4.z + e4.z) * oscale);
        o.w = f2bf((a[3] + b4.w + e4.w) * oscale);
        *(ushort4*)&wsq[obase + (size_t)(bh*SS + s_)*HDD + d0] = o;
      }
    }
  }
}

// ---------------- kernel 3: flash attention, 32q/wave, 8-wave blocks ----------------
// R12: (a) KVBLK=64 (2 sub-chunks of 32/stage) -> 32 barriers (was 64).
// (b) V LDS rows now 128B ([64 d][64 kt]) with XOR piece-swizzle p'=p^(row&7) via
//     pre-swizzled SOURCE (rule 21): V-read was an 8-way bank conflict (4.19M cy,
//     R11 counters) -> 16 lanes now spread across all 32 banks (2-way, free).
//     K swizzle unchanged (row&7 == l15&7 still, since sub*32+fi*16 ≡ 0 mod 8).
// (c) row-sums via MFMA: lsum = mfma(ones, bp, lsum) accumulates sum_kt P̃[kt][q]
//     per q=l15 (C[m][q] independent of m) -> removes 16 VALU adds/chunk and the
//     epilogue shfl reduce. Denominator now sums bf16-rounded P — self-consistent
//     with the numerator (weights sum to exactly 1).
#define LOG2E_F 1.4426950408889634f
__global__ __launch_bounds__(512) void attn_mfma(
    const unsigned short* __restrict__ ws16,
    const float* __restrict__ mask, float* __restrict__ out){
  __shared__ __align__(16) unsigned short kb[2][64*64];   // [kt][d], swizzled, 2x8KB
  __shared__ __align__(16) unsigned short vb[2][64*64];   // [d][kt], swizzled, 2x8KB
  __shared__ __align__(16) float mlds[SS];                // mask row * log2e, 8KB

  const int tid  = threadIdx.x;
  const int wave = tid >> 6;
  const int lane = tid & 63;
  const int quad = lane >> 4;
  const int l15  = lane & 15;

  // XCD-aware swizzle (bijective: 512 % 8 == 0): each head's 8 blocks on one XCD.
  const int bid  = (blockIdx.x & 7)*64 + (blockIdx.x >> 3);
  const int qb   = bid & 7;                  // 8 q-blocks of 256 rows per bh
  const int bh   = bid >> 3;
  const int b    = bh >> 4, h = bh & 15;
  const int q0   = qb*256 + wave*32;         // this wave's first q row

  const unsigned short* Qg = ws16 + Q_OFF  + (size_t)bh*SS*HDD;
  const unsigned short* Kg = ws16 + K_OFF  + (size_t)bh*SS*HDD;
  const unsigned short* Vg = ws16 + VT_OFF + (size_t)bh*HDD*SS;
  const float* maskB = mask + b*SS;

  // stage mask row * log2e (512 threads x float4 = 8KB)
  {
    float4 m4 = ((const float4*)maskB)[tid];
    m4.x*=LOG2E_F; m4.y*=LOG2E_F; m4.z*=LOG2E_F; m4.w*=LOG2E_F;
    *(float4*)&mlds[tid*4] = m4;
  }

  // resident Q fragments: B-operand (n=q=qg*16+l15, k=d=h2*32+quad*8+j)
  bf16x8 aq[2][2];
  #pragma unroll
  for (int qg = 0; qg < 2; qg++)
    #pragma unroll
    for (int h2 = 0; h2 < 2; h2++)
      aq[qg][h2] = *(const bf16x8*)(Qg + (size_t)(q0 + qg*16 + l15)*HDD + h2*32 + quad*8);

  // ones A-fragment for row-sum MFMA (bf16 1.0 = 0x3F80)
  bf16x8 ones;
  #pragma unroll
  for (int j = 0; j < 8; j++) ones[j] = (short)0x3F80;

  // staging role split (2 x 16B loads/thread/chunk):
  //  waves 0-3: K chunk = 64 kt-rows x 128B. kr = tid>>3 (rows 0-31 + 32), kp = tid&7.
  //    source col pre-XOR-swizzled: (kp*16) ^ ((kr&7)<<4) bytes; (kr+32)&7 == kr&7.
  //  waves 4-7: V chunk = 64 d-rows x 128B (64 kt). vr = t>>3, vp = t&7; source kt
  //    offset = (vp ^ (vr&7))*8 elements; rows vr and vr+32 share vr&7.
  const unsigned short* sSrc0;
  const unsigned short* sSrc1;
  unsigned short* sDst;
  int sAdv;
  if (tid < 256){
    const int kr = tid >> 3, kp = tid & 7;
    sSrc0 = Kg + (size_t)kr*HDD + ((((kp*16) ^ ((kr&7)<<4)))>>1);
    sSrc1 = sSrc0 + 32*HDD;
    sDst  = &kb[0][0] + tid*8;               // 16B per thread, linear
    sAdv  = 64*HDD;                          // next 64 kt rows
  } else {
    const int t = tid - 256;
    const int vr = t >> 3, vp = t & 7;
    sSrc0 = Vg + (size_t)vr*SS + (vp ^ (vr&7))*8;
    sSrc1 = sSrc0 + 32*SS;
    sDst  = &vb[0][0] + t*8;
    sAdv  = 64;                              // next 64 kt cols
  }

  f32x4 O[4][2] = {};            // O^T: elem (d=dg*16+quad*4+r, q=qg*16+l15)
  f32x4 lsum[2] = {};            // row-sums via MFMA: all elems hold sum for q=l15

  // prologue: stage chunk 0 into buffer 0 (syncthreads drains vmcnt)
  ld_g2l_16(sSrc0, sDst);
  ld_g2l_16(sSrc1, sDst + 2048);
  sSrc0 += sAdv; sSrc1 += sAdv;
  __syncthreads();

  for (int ch = 0; ch < 32; ++ch){
    const int cur = ch & 1;
    const int ktb = ch*64;
    if (ch < 31){                // issue next-chunk stage BEFORE compute (overlap)
      ld_g2l_16(sSrc0, sDst + (cur^1)*4096);
      ld_g2l_16(sSrc1, sDst + (cur^1)*4096 + 2048);
      sSrc0 += sAdv; sSrc1 += sAdv;
    }
    const unsigned short* kcur = &kb[cur][0];
    const unsigned short* vcur = &vb[cur][0];

    #pragma unroll
    for (int sub = 0; sub < 2; ++sub){
      // K fragments: A-operand (m=kt=sub*32+fi*16+l15, k=d), swizzled (conflict-free)
      bf16x8 ka[2][2];
      #pragma unroll
      for (int fi = 0; fi < 2; fi++)
        #pragma unroll
        for (int h2 = 0; h2 < 2; h2++){
          const int row  = sub*32 + fi*16 + l15;
          const int colb = (h2*64 + quad*16) ^ ((l15 & 7) << 4);
          ka[fi][h2] = *(const bf16x8*)&kcur[row*64 + (colb>>1)];
        }

      // S^T = K·Q^T with C init = mask*log2e -> p = exp2(st) -> pk pairs
      unsigned A0[2], A1[2], B0[2], B1[2];   // [qg]
      #pragma unroll
      for (int fi = 0; fi < 2; fi++){
        const f32x4 mv = *(const f32x4*)&mlds[ktb + sub*32 + fi*16 + quad*4];
        #pragma unroll
        for (int qg = 0; qg < 2; qg++){
          f32x4 st = mv;
          st = __builtin_amdgcn_mfma_f32_16x16x32_bf16(ka[fi][0], aq[qg][0], st, 0,0,0);
          st = __builtin_amdgcn_mfma_f32_16x16x32_bf16(ka[fi][1], aq[qg][1], st, 0,0,0);
          f32x4 p;
          #pragma unroll
          for (int r = 0; r < 4; r++) p[r] = __builtin_amdgcn_exp2f(st[r]);
          const unsigned lo = pk2bf(p[0], p[1]), hi = pk2bf(p[2], p[3]);
          if (fi == 0){ A0[qg] = lo; A1[qg] = hi; }
          else        { B0[qg] = lo; B1[qg] = hi; }
        }
      }

      // V^T fragments: A-operand (m=d=dg*16+l15, k=kt=sub*32+quad*8+j), swizzled read
      bf16x8 va[4];
      #pragma unroll
      for (int dg = 0; dg < 4; dg++){
        const int row   = dg*16 + l15;
        const int piece = (sub*4 + quad) ^ (l15 & 7);
        va[dg] = *(const bf16x8*)&vcur[row*64 + piece*8];
      }

      // in-register P redistribution (T12) + PV + row-sum MFMA, per qg
      #pragma unroll
      for (int qg = 0; qg < 2; qg++){
        uint32x2 x   = __builtin_amdgcn_permlane32_swap(A0[qg], B0[qg], 0, 0);
        uint32x2 y   = __builtin_amdgcn_permlane32_swap(A1[qg], B1[qg], 0, 0);
        uint32x2 w02 = __builtin_amdgcn_permlane16_swap(x[0], x[1], 0, 0); // w0, w2
        uint32x2 w13 = __builtin_amdgcn_permlane16_swap(y[0], y[1], 0, 0); // w1, w3
        union { unsigned u[4]; bf16x8 v; } bpu;
        bpu.u[0] = w02[0]; bpu.u[1] = w13[0]; bpu.u[2] = w02[1]; bpu.u[3] = w13[1];
        const bf16x8 bp = bpu.v;
        #pragma unroll
        for (int dg = 0; dg < 4; dg++)
          O[dg][qg] = __builtin_amdgcn_mfma_f32_16x16x32_bf16(va[dg], bp, O[dg][qg], 0,0,0);
        lsum[qg] = __builtin_amdgcn_mfma_f32_16x16x32_bf16(ones, bp, lsum[qg], 0,0,0);
      }
    }

    __syncthreads();   // all waves done reading cur; next-chunk stage drained
  }

  // epilogue: inv = 1/sum (lsum[qg][r] identical for all r and all lanes w/ same l15)
  #pragma unroll
  for (int qg = 0; qg < 2; qg++){
    const float inv = 1.0f / lsum[qg][0];
    float* op = out + ((size_t)b*SS + q0 + qg*16 + l15)*HH + h*HDD + quad*4;
    #pragma unroll
    for (int dg = 0; dg < 4; dg++){
      f32x4 v = O[dg][qg];
      float4 o; o.x = v[0]*inv; o.y = v[1]*inv; o.z = v[2]*inv; o.w = v[3]*inv;
      *(float4*)(op + dg*16) = o;
    }
  }
}

extern "C" void kernel_launch(void* const* d_in, const int* in_sizes, int n_in,
                              void* d_out, int out_size, void* d_ws, size_t ws_size,
                              hipStream_t stream){
  const float* hs   = (const float*)d_in[0];
  const float* mask = (const float*)d_in[1];
  const float* Wq   = (const float*)d_in[2];
  const float* bq   = (const float*)d_in[3];
  const float* Wk   = (const float*)d_in[4];
  const float* bk   = (const float*)d_in[5];
  const float* Wv   = (const float*)d_in[6];
  const float* bv   = (const float*)d_in[7];
  const float* qe   = (const float*)d_in[8];
  const float* ke   = (const float*)d_in[9];
  const float* ve   = (const float*)d_in[10];
  const int*   idx  = (const int*)d_in[11];
  unsigned short* ws16 = (unsigned short*)d_ws;
  float* out = (float*)d_out;

  convert_all<<<8192 + 768, 256, 0, stream>>>(hs, ws16 + XB_OFF, Wq, Wk, Wv, ws16 + WT_OFF);

  dim3 g2(M_TOT/256, HH/128, 3);
  qkv_gemm<<<g2, 512, 0, stream>>>(ws16, ws16, bq, bk, bv, qe, ke, ve, idx);

  attn_mfma<<<BB*NHH*SS/256, 512, 0, stream>>>(ws16, mask, out);
}